// Round 1
// baseline (5795.444 us; speedup 1.0000x reference)
//
#include <hip/hip_runtime.h>
#include <hip/hip_bf16.h>

#define NNODES 20000
#define NEDGES 640000
#define DM 256

// ---------------- gather: x = entity_embeddings[concept_ids] ----------------
__global__ __launch_bounds__(256) void gather_kernel(
    const int* __restrict__ cid, const float* __restrict__ ent,
    float* __restrict__ x, int n) {
  int idx = blockIdx.x * 256 + threadIdx.x;
  if (idx >= n * 64) return;
  int node = idx >> 6, d4 = idx & 63;
  float4 v = reinterpret_cast<const float4*>(ent)[(size_t)cid[node] * 64 + d4];
  reinterpret_cast<float4*>(x)[(size_t)node * 64 + d4] = v;
}

// ---------------- generic f32 GEMM: C = A@B + bias (+ resid) ----------------
// A[M,K], B[K,N] row-major. N % 64 == 0, K % 16 == 0. Tile 64x64x16, 4x4/thread.
__global__ __launch_bounds__(256) void gemm_f32_kernel(
    const float* __restrict__ A, const float* __restrict__ B,
    const float* __restrict__ bias, const float* __restrict__ resid,
    float* __restrict__ C, int M, int N, int K) {
  __shared__ float As[16][68];
  __shared__ float Bs[16][68];
  int tx = threadIdx.x, ty = threadIdx.y;
  int tid = ty * 16 + tx;
  int rowBase = blockIdx.y * 64;
  int colBase = blockIdx.x * 64;
  float acc[4][4] = {};
  for (int k0 = 0; k0 < K; k0 += 16) {
#pragma unroll
    for (int i = 0; i < 4; i++) {
      int idx = tid + i * 256;
      int m = idx >> 4, kk = idx & 15;
      int gr = rowBase + m;
      As[kk][m] = (gr < M) ? A[(size_t)gr * K + (k0 + kk)] : 0.f;
    }
#pragma unroll
    for (int i = 0; i < 4; i++) {
      int idx = tid + i * 256;
      int kk = idx >> 6, n = idx & 63;
      Bs[kk][n] = B[(size_t)(k0 + kk) * N + colBase + n];
    }
    __syncthreads();
#pragma unroll
    for (int kk = 0; kk < 16; kk++) {
      float a[4], b[4];
#pragma unroll
      for (int i = 0; i < 4; i++) a[i] = As[kk][ty * 4 + i];
#pragma unroll
      for (int j = 0; j < 4; j++) b[j] = Bs[kk][tx * 4 + j];
#pragma unroll
      for (int i = 0; i < 4; i++)
#pragma unroll
        for (int j = 0; j < 4; j++) acc[i][j] += a[i] * b[j];
    }
    __syncthreads();
  }
#pragma unroll
  for (int i = 0; i < 4; i++) {
    int r = rowBase + ty * 4 + i;
    if (r >= M) continue;
#pragma unroll
    for (int j = 0; j < 4; j++) {
      int c = colBase + tx * 4 + j;
      float v = acc[i][j];
      if (bias) v += bias[c];
      if (resid) v += resid[(size_t)r * N + c];
      C[(size_t)r * N + c] = v;
    }
  }
}

// ---------------- QS5 = sentence_embeddings @ Ws[l] + bs[l]  (5x256) --------
__global__ __launch_bounds__(256) void qs5_kernel(
    const float* __restrict__ sent, const float* __restrict__ Ws,
    const float* __restrict__ bs, float* __restrict__ QS5) {
  int g = blockIdx.x;
  int j = threadIdx.x;
  float acc = bs[j];
  for (int k = 0; k < 1024; k++) acc += sent[g * 1024 + k] * Ws[k * 256 + j];
  QS5[g * 256 + j] = acc;
}

// ---------------- edge scores + global per-head sum of exp ------------------
// wave per edge-group of 16; lanes cover 256 channels (4 each); head = lane/16.
__global__ __launch_bounds__(256) void edge_score_kernel(
    const int* __restrict__ ei, const int* __restrict__ batch,
    const float* __restrict__ Q, const float* __restrict__ K,
    const float* __restrict__ QS5, float* __restrict__ s,
    float* __restrict__ sums, int E) {
  int wave = (blockIdx.x * 256 + threadIdx.x) >> 6;
  int lane = threadIdx.x & 63;
  int head = lane >> 4;
  float sumExp = 0.f;
  int e0 = wave * 16;
  for (int i = 0; i < 16; i++) {
    int e = e0 + i;
    if (e >= E) break;
    int r = ei[e], c = ei[E + e];
    int gr = batch[r] / 5, gc = batch[c] / 5;
    float4 q = reinterpret_cast<const float4*>(Q)[(size_t)r * 64 + lane];
    float4 k = reinterpret_cast<const float4*>(K)[(size_t)c * 64 + lane];
    float4 qr = reinterpret_cast<const float4*>(QS5)[gr * 64 + lane];
    float4 qc = reinterpret_cast<const float4*>(QS5)[gc * 64 + lane];
    float p = (q.x + qr.x) * k.x + (q.y + qr.y) * k.y + (q.z + qr.z) * k.z +
              (q.w + qr.w) * k.w + q.x * qc.x + q.y * qc.y + q.z * qc.z +
              q.w * qc.w;
    p += __shfl_xor(p, 1);
    p += __shfl_xor(p, 2);
    p += __shfl_xor(p, 4);
    p += __shfl_xor(p, 8);
    float v = p / 24.f;
    v = (v >= 0.f) ? v : 0.2f * v;
    if ((lane & 15) == 0) {
      s[(size_t)e * 4 + head] = v;
      sumExp += expf(v);
    }
  }
  __shared__ float red[4][4];
  int w = threadIdx.x >> 6;
  if ((lane & 15) == 0) red[w][head] = sumExp;
  __syncthreads();
  if (threadIdx.x < 4) {
    float t = red[0][threadIdx.x] + red[1][threadIdx.x] + red[2][threadIdx.x] +
              red[3][threadIdx.x];
    atomicAdd(&sums[threadIdx.x], t);
  }
}

// ---------------- scatter: agg[row] += V[col] * softmax_weight --------------
__global__ __launch_bounds__(256) void edge_scatter_kernel(
    const int* __restrict__ ei, const float* __restrict__ V,
    const float* __restrict__ s, const float* __restrict__ sums,
    float* __restrict__ agg, int E) {
  int wave = (blockIdx.x * 256 + threadIdx.x) >> 6;
  int lane = threadIdx.x & 63;
  int head = lane >> 4;
  float invS = 1.f / sums[head];
  int e0 = wave * 16;
  for (int i = 0; i < 16; i++) {
    int e = e0 + i;
    if (e >= E) break;
    int r = ei[e], c = ei[E + e];
    float w = expf(s[(size_t)e * 4 + head]) * invS;
    float4 v = reinterpret_cast<const float4*>(V)[(size_t)c * 64 + lane];
    float* dst = agg + (size_t)r * 256 + lane * 4;
    atomicAdd(dst + 0, v.x * w);
    atomicAdd(dst + 1, v.y * w);
    atomicAdd(dst + 2, v.z * w);
    atomicAdd(dst + 3, v.w * w);
  }
}

// ---------------- layer-2 shortcut: only agg[0] is needed -------------------
__global__ __launch_bounds__(256) void compact_row0_kernel(
    const int* __restrict__ ei, int* __restrict__ cnt_list, int E) {
  int e = blockIdx.x * 256 + threadIdx.x;
  if (e < E && ei[e] == 0) {
    int p = atomicAdd(cnt_list, 1);
    if (p < 4095) cnt_list[1 + p] = e;
  }
}

__global__ __launch_bounds__(64) void scatter_row0_kernel(
    const int* __restrict__ ei, const float* __restrict__ V,
    const float* __restrict__ s, const float* __restrict__ sums,
    const int* __restrict__ cnt_list, float* __restrict__ agg0, int E) {
  int lane = threadIdx.x;
  int head = lane >> 4;
  float invS = 1.f / sums[head];
  int cnt = cnt_list[0];
  if (cnt > 4095) cnt = 4095;
  for (int m = blockIdx.x; m < cnt; m += gridDim.x) {
    int e = cnt_list[1 + m];
    int c = ei[E + e];
    float w = expf(s[(size_t)e * 4 + head]) * invS;
    float4 v = reinterpret_cast<const float4*>(V)[(size_t)c * 64 + lane];
    float* dst = agg0 + lane * 4;
    atomicAdd(dst + 0, v.x * w);
    atomicAdd(dst + 1, v.y * w);
    atomicAdd(dst + 2, v.z * w);
    atomicAdd(dst + 3, v.w * w);
  }
}

// x1 = ((agg0 @ Wo2 + bo2 + x[0]) @ W1 + b1)
__global__ __launch_bounds__(256) void final_head_kernel(
    const float* __restrict__ agg0, const float* __restrict__ Wo2,
    const float* __restrict__ bo2, const float* __restrict__ x,
    const float* __restrict__ W1, const float* __restrict__ b1,
    float* __restrict__ x1) {
  __shared__ float a0[256];
  __shared__ float t1[256];
  int j = threadIdx.x;
  a0[j] = agg0[j];
  __syncthreads();
  float acc = bo2[j] + x[j];
  for (int k = 0; k < 256; k++) acc += a0[k] * Wo2[k * 256 + j];
  t1[j] = acc;
  __syncthreads();
  float acc2 = b1[j];
  for (int k = 0; k < 256; k++) acc2 += t1[k] * W1[k * 256 + j];
  x1[j] = acc2;
}

// ---------------- AO[b] = softmax_t(x1 . tok[b,t] / 16) @ tok[b] ------------
__global__ __launch_bounds__(256) void attn_out_kernel(
    const float* __restrict__ x1g, const float* __restrict__ tok,
    float* __restrict__ AO) {
  int b = blockIdx.x;
  int t = threadIdx.x;
  __shared__ float x1[256];
  __shared__ float w[256];
  __shared__ float red[256];
  x1[t] = x1g[t];
  __syncthreads();
  const float* tr = tok + (size_t)(b * 256 + t) * 256;
  float sc = 0.f;
  for (int d = 0; d < 256; d++) sc += x1[d] * tr[d];
  sc *= (1.f / 16.f);
  red[t] = sc;
  __syncthreads();
  for (int off = 128; off; off >>= 1) {
    if (t < off) red[t] = fmaxf(red[t], red[t + off]);
    __syncthreads();
  }
  float mx = red[0];
  __syncthreads();
  float ex = expf(sc - mx);
  red[t] = ex;
  __syncthreads();
  for (int off = 128; off; off >>= 1) {
    if (t < off) red[t] += red[t + off];
    __syncthreads();
  }
  w[t] = ex / red[0];
  __syncthreads();
  float acc = 0.f;
  for (int k = 0; k < 256; k++) acc += w[k] * tok[(size_t)(b * 256 + k) * 256 + t];
  AO[b * 256 + t] = acc;
}

// ---------------- y = AOflat @ Wout + bout; out_row = y @ W3 + b3; tile 25 --
__global__ __launch_bounds__(256) void final_out_kernel(
    const float* __restrict__ AO, const float* __restrict__ Wout,
    const float* __restrict__ bout, const float* __restrict__ W3,
    const float* __restrict__ b3, float* __restrict__ out) {
  __shared__ float a[1280];
  __shared__ float y[256];
  int j = threadIdx.x;
  for (int i = j; i < 1280; i += 256) a[i] = AO[i];
  __syncthreads();
  float acc = bout[j];
  for (int k = 0; k < 1280; k++) acc += a[k] * Wout[k * 256 + j];
  y[j] = acc;
  __syncthreads();
  for (int q = 0; q < 4; q++) {
    int t = j + q * 256;
    float o = b3[t];
    for (int k = 0; k < 256; k++) o += y[k] * W3[k * 1024 + t];
    for (int g = 0; g < 25; g++) out[(size_t)g * 1024 + t] = o;
  }
}

extern "C" void kernel_launch(void* const* d_in, const int* in_sizes, int n_in,
                              void* d_out, int out_size, void* d_ws,
                              size_t ws_size, hipStream_t stream) {
  const int* concept_ids = (const int*)d_in[0];
  const int* edge_index = (const int*)d_in[1];
  // d_in[2] edge_type: unused by reference
  const float* sent = (const float*)d_in[3];
  const float* tokemb = (const float*)d_in[4];
  const int* batch = (const int*)d_in[5];
  const float* ent = (const float*)d_in[6];
  const float* Wq = (const float*)d_in[7];
  const float* bq = (const float*)d_in[8];
  const float* Wk = (const float*)d_in[9];
  const float* bk = (const float*)d_in[10];
  const float* Wv = (const float*)d_in[11];
  const float* bv = (const float*)d_in[12];
  const float* Ws = (const float*)d_in[13];
  const float* bs = (const float*)d_in[14];
  const float* Wo = (const float*)d_in[15];
  const float* bo = (const float*)d_in[16];
  const float* W1 = (const float*)d_in[17];
  const float* b1 = (const float*)d_in[18];
  const float* W2 = (const float*)d_in[19];
  const float* b2 = (const float*)d_in[20];
  const float* W3 = (const float*)d_in[21];
  const float* b3 = (const float*)d_in[22];
  const float* Wout = (const float*)d_in[23];
  const float* bout = (const float*)d_in[24];
  float* out = (float*)d_out;

  float* ws = (float*)d_ws;
  size_t off = 0;
  auto alloc = [&](size_t n) {
    float* p = ws + off;
    off += n;
    return p;
  };
  float* x = alloc((size_t)NNODES * DM);
  float* x2 = alloc((size_t)NNODES * DM);
  float* Qb = alloc((size_t)NNODES * DM);  // reused as agg after scores
  float* Kb = alloc((size_t)NNODES * DM);
  float* Vb = alloc((size_t)NNODES * DM);
  float* s = alloc((size_t)NEDGES * 4);
  float* tok = alloc(1280 * 256);
  float* QS5 = alloc(5 * 256);
  float* sums = alloc(4);
  float* agg0 = alloc(256);
  float* x1 = alloc(256);
  float* AO = alloc(1280);
  int* cnt_list = (int*)alloc(4100);

  dim3 gblk(16, 16);

  // x = entity_embeddings[concept_ids]
  gather_kernel<<<(NNODES * 64 + 255) / 256, 256, 0, stream>>>(concept_ids, ent,
                                                               x, NNODES);

  float* xin = x;
  float* xout = x2;
  for (int l = 0; l < 3; l++) {
    const float* Wql = Wq + (size_t)l * DM * DM;
    const float* Wkl = Wk + (size_t)l * DM * DM;
    const float* Wvl = Wv + (size_t)l * DM * DM;
    const float* Wsl = Ws + (size_t)l * 1024 * DM;
    const float* Wol = Wo + (size_t)l * DM * DM;

    dim3 grid(DM / 64, (NNODES + 63) / 64);
    gemm_f32_kernel<<<grid, gblk, 0, stream>>>(xin, Wql, bq + l * DM, nullptr,
                                               Qb, NNODES, DM, DM);
    gemm_f32_kernel<<<grid, gblk, 0, stream>>>(xin, Wkl, bk + l * DM, nullptr,
                                               Kb, NNODES, DM, DM);
    gemm_f32_kernel<<<grid, gblk, 0, stream>>>(xin, Wvl, bv + l * DM, nullptr,
                                               Vb, NNODES, DM, DM);
    qs5_kernel<<<5, 256, 0, stream>>>(sent, Wsl, bs + l * DM, QS5);

    hipMemsetAsync(sums, 0, 4 * sizeof(float), stream);
    edge_score_kernel<<<10000, 256, 0, stream>>>(edge_index, batch, Qb, Kb, QS5,
                                                 s, sums, NEDGES);
    if (l < 2) {
      // agg aliases Qb (Q no longer needed)
      hipMemsetAsync(Qb, 0, (size_t)NNODES * DM * sizeof(float), stream);
      edge_scatter_kernel<<<10000, 256, 0, stream>>>(edge_index, Vb, s, sums,
                                                     Qb, NEDGES);
      gemm_f32_kernel<<<grid, gblk, 0, stream>>>(Qb, Wol, bo + l * DM, xin,
                                                 xout, NNODES, DM, DM);
      float* tmp = xin;
      xin = xout;
      xout = tmp;
    } else {
      hipMemsetAsync(cnt_list, 0, sizeof(int), stream);
      hipMemsetAsync(agg0, 0, 256 * sizeof(float), stream);
      compact_row0_kernel<<<(NEDGES + 255) / 256, 256, 0, stream>>>(
          edge_index, cnt_list, NEDGES);
      scatter_row0_kernel<<<64, 64, 0, stream>>>(edge_index, Vb, s, sums,
                                                 cnt_list, agg0, NEDGES);
      final_head_kernel<<<1, 256, 0, stream>>>(agg0, Wol, bo + 2 * DM, xin, W1,
                                               b1, x1);
    }
  }

  // tok = token_embedding(1280x1024) @ W2 + b2
  {
    dim3 grid(DM / 64, 1280 / 64);
    gemm_f32_kernel<<<grid, gblk, 0, stream>>>(tokemb, W2, b2, nullptr, tok,
                                               1280, DM, 1024);
  }
  attn_out_kernel<<<5, 256, 0, stream>>>(x1, tok, AO);
  final_out_kernel<<<1, 256, 0, stream>>>(AO, Wout, bout, W3, b3, out);
}

// Round 2
// 1870.823 us; speedup vs baseline: 3.0978x; 3.0978x over previous
//
#include <hip/hip_runtime.h>
#include <hip/hip_bf16.h>

#define NNODES 20000
#define NEDGES 640000
#define DM 256

// ---------------- gather: x = entity_embeddings[concept_ids] ----------------
__global__ __launch_bounds__(256) void gather_kernel(
    const int* __restrict__ cid, const float* __restrict__ ent,
    float* __restrict__ x, int n) {
  int idx = blockIdx.x * 256 + threadIdx.x;
  if (idx >= n * 64) return;
  int node = idx >> 6, d4 = idx & 63;
  float4 v = reinterpret_cast<const float4*>(ent)[(size_t)cid[node] * 64 + d4];
  reinterpret_cast<float4*>(x)[(size_t)node * 64 + d4] = v;
}

// ---------------- generic f32 GEMM: C = A@B + bias (+ resid) ----------------
__global__ __launch_bounds__(256) void gemm_f32_kernel(
    const float* __restrict__ A, const float* __restrict__ B,
    const float* __restrict__ bias, const float* __restrict__ resid,
    float* __restrict__ C, int M, int N, int K) {
  __shared__ float As[16][68];
  __shared__ float Bs[16][68];
  int tx = threadIdx.x, ty = threadIdx.y;
  int tid = ty * 16 + tx;
  int rowBase = blockIdx.y * 64;
  int colBase = blockIdx.x * 64;
  float acc[4][4] = {};
  for (int k0 = 0; k0 < K; k0 += 16) {
#pragma unroll
    for (int i = 0; i < 4; i++) {
      int idx = tid + i * 256;
      int m = idx >> 4, kk = idx & 15;
      int gr = rowBase + m;
      As[kk][m] = (gr < M) ? A[(size_t)gr * K + (k0 + kk)] : 0.f;
    }
#pragma unroll
    for (int i = 0; i < 4; i++) {
      int idx = tid + i * 256;
      int kk = idx >> 6, n = idx & 63;
      Bs[kk][n] = B[(size_t)(k0 + kk) * N + colBase + n];
    }
    __syncthreads();
#pragma unroll
    for (int kk = 0; kk < 16; kk++) {
      float a[4], b[4];
#pragma unroll
      for (int i = 0; i < 4; i++) a[i] = As[kk][ty * 4 + i];
#pragma unroll
      for (int j = 0; j < 4; j++) b[j] = Bs[kk][tx * 4 + j];
#pragma unroll
      for (int i = 0; i < 4; i++)
#pragma unroll
        for (int j = 0; j < 4; j++) acc[i][j] += a[i] * b[j];
    }
    __syncthreads();
  }
#pragma unroll
  for (int i = 0; i < 4; i++) {
    int r = rowBase + ty * 4 + i;
    if (r >= M) continue;
#pragma unroll
    for (int j = 0; j < 4; j++) {
      int c = colBase + tx * 4 + j;
      float v = acc[i][j];
      if (bias) v += bias[c];
      if (resid) v += resid[(size_t)r * N + c];
      C[(size_t)r * N + c] = v;
    }
  }
}

// ---------------- QS5 = sentence_embeddings @ Ws[l] + bs[l]  (5x256) --------
__global__ __launch_bounds__(256) void qs5_kernel(
    const float* __restrict__ sent, const float* __restrict__ Ws,
    const float* __restrict__ bs, float* __restrict__ QS5) {
  int g = blockIdx.x;
  int j = threadIdx.x;
  float acc = bs[j];
  for (int k = 0; k < 1024; k++) acc += sent[g * 1024 + k] * Ws[k * 256 + j];
  QS5[g * 256 + j] = acc;
}

// ---------------- CSR build ----------------
__global__ __launch_bounds__(256) void deg_kernel(const int* __restrict__ ei,
                                                  int* __restrict__ deg, int E) {
  int e = blockIdx.x * 256 + threadIdx.x;
  if (e < E) atomicAdd(&deg[ei[e]], 1);
}

__global__ __launch_bounds__(256) void scan_kernel(const int* __restrict__ deg,
                                                   int* __restrict__ off,
                                                   int n) {
  __shared__ int buf[256];
  __shared__ int carry;
  if (threadIdx.x == 0) carry = 0;
  __syncthreads();
  for (int base = 0; base < n; base += 256) {
    int i = base + threadIdx.x;
    int v = (i < n) ? deg[i] : 0;
    buf[threadIdx.x] = v;
    __syncthreads();
    for (int ofs = 1; ofs < 256; ofs <<= 1) {
      int t = (threadIdx.x >= ofs) ? buf[threadIdx.x - ofs] : 0;
      __syncthreads();
      buf[threadIdx.x] += t;
      __syncthreads();
    }
    if (i < n) off[i] = carry + buf[threadIdx.x] - v;
    __syncthreads();
    if (threadIdx.x == 255) carry += buf[255];
    __syncthreads();
  }
  if (threadIdx.x == 0) off[n] = carry;
}

__global__ __launch_bounds__(256) void fill_kernel(const int* __restrict__ ei,
                                                   int* __restrict__ cursor,
                                                   int* __restrict__ perm,
                                                   int* __restrict__ colPerm,
                                                   int E) {
  int e = blockIdx.x * 256 + threadIdx.x;
  if (e >= E) return;
  int r = ei[e];
  int pos = atomicAdd(&cursor[r], 1);
  perm[e] = pos;
  colPerm[pos] = ei[E + e];
}

// ---------------- edge scores + global per-head sum of exp ------------------
// Writes exp(leaky(score)) into CSR-permuted slot.
__global__ __launch_bounds__(256) void edge_score_kernel(
    const int* __restrict__ ei, const int* __restrict__ batch,
    const float* __restrict__ Q, const float* __restrict__ K,
    const float* __restrict__ QS5, const int* __restrict__ perm,
    float* __restrict__ sExp, float* __restrict__ sums, int E) {
  int wave = (blockIdx.x * 256 + threadIdx.x) >> 6;
  int lane = threadIdx.x & 63;
  int head = lane >> 4;
  float sumExp = 0.f;
  int e0 = wave * 16;
  for (int i = 0; i < 16; i++) {
    int e = e0 + i;
    if (e >= E) break;
    int r = ei[e], c = ei[E + e];
    int gr = batch[r] / 5, gc = batch[c] / 5;
    float4 q = reinterpret_cast<const float4*>(Q)[(size_t)r * 64 + lane];
    float4 k = reinterpret_cast<const float4*>(K)[(size_t)c * 64 + lane];
    float4 qr = reinterpret_cast<const float4*>(QS5)[gr * 64 + lane];
    float4 qc = reinterpret_cast<const float4*>(QS5)[gc * 64 + lane];
    float p = (q.x + qr.x) * k.x + (q.y + qr.y) * k.y + (q.z + qr.z) * k.z +
              (q.w + qr.w) * k.w + q.x * qc.x + q.y * qc.y + q.z * qc.z +
              q.w * qc.w;
    p += __shfl_xor(p, 1);
    p += __shfl_xor(p, 2);
    p += __shfl_xor(p, 4);
    p += __shfl_xor(p, 8);
    float v = p / 24.f;
    v = (v >= 0.f) ? v : 0.2f * v;
    if ((lane & 15) == 0) {
      float ev = expf(v);
      sExp[(size_t)perm[e] * 4 + head] = ev;
      sumExp += ev;
    }
  }
  __shared__ float red[4][4];
  int w = threadIdx.x >> 6;
  if ((lane & 15) == 0) red[w][head] = sumExp;
  __syncthreads();
  if (threadIdx.x < 4) {
    float t = red[0][threadIdx.x] + red[1][threadIdx.x] + red[2][threadIdx.x] +
              red[3][threadIdx.x];
    atomicAdd(&sums[threadIdx.x], t);
  }
}

// ---------------- CSR gather: agg[r] = sum_in-edges exp(s)*V[col] / sum ------
// one wave per node; lane covers 4 channels (float4), head = lane/16.
__global__ __launch_bounds__(256) void gather_agg_kernel(
    const int* __restrict__ off, const int* __restrict__ colPerm,
    const float* __restrict__ sExp, const float* __restrict__ sums,
    const float* __restrict__ V, float* __restrict__ agg, int n) {
  int node = (blockIdx.x * 256 + threadIdx.x) >> 6;
  if (node >= n) return;
  int lane = threadIdx.x & 63;
  int head = lane >> 4;
  int s0 = off[node], s1 = off[node + 1];
  float4 acc = {0.f, 0.f, 0.f, 0.f};
  for (int m = s0; m < s1; m++) {
    float w = sExp[(size_t)m * 4 + head];
    int c = colPerm[m];
    float4 v = reinterpret_cast<const float4*>(V)[(size_t)c * 64 + lane];
    acc.x += v.x * w;
    acc.y += v.y * w;
    acc.z += v.z * w;
    acc.w += v.w * w;
  }
  float invS = 1.f / sums[head];
  acc.x *= invS;
  acc.y *= invS;
  acc.z *= invS;
  acc.w *= invS;
  reinterpret_cast<float4*>(agg)[(size_t)node * 64 + lane] = acc;
}

// x1 = ((agg0 @ Wo2 + bo2 + x[0]) @ W1 + b1)
__global__ __launch_bounds__(256) void final_head_kernel(
    const float* __restrict__ agg0, const float* __restrict__ Wo2,
    const float* __restrict__ bo2, const float* __restrict__ x,
    const float* __restrict__ W1, const float* __restrict__ b1,
    float* __restrict__ x1) {
  __shared__ float a0[256];
  __shared__ float t1[256];
  int j = threadIdx.x;
  a0[j] = agg0[j];
  __syncthreads();
  float acc = bo2[j] + x[j];
  for (int k = 0; k < 256; k++) acc += a0[k] * Wo2[k * 256 + j];
  t1[j] = acc;
  __syncthreads();
  float acc2 = b1[j];
  for (int k = 0; k < 256; k++) acc2 += t1[k] * W1[k * 256 + j];
  x1[j] = acc2;
}

// ---------------- AO[b] = softmax_t(x1 . tok[b,t] / 16) @ tok[b] ------------
__global__ __launch_bounds__(256) void attn_out_kernel(
    const float* __restrict__ x1g, const float* __restrict__ tok,
    float* __restrict__ AO) {
  int b = blockIdx.x;
  int t = threadIdx.x;
  __shared__ float x1[256];
  __shared__ float w[256];
  __shared__ float red[256];
  x1[t] = x1g[t];
  __syncthreads();
  const float* tr = tok + (size_t)(b * 256 + t) * 256;
  float sc = 0.f;
  for (int d = 0; d < 256; d++) sc += x1[d] * tr[d];
  sc *= (1.f / 16.f);
  red[t] = sc;
  __syncthreads();
  for (int off = 128; off; off >>= 1) {
    if (t < off) red[t] = fmaxf(red[t], red[t + off]);
    __syncthreads();
  }
  float mx = red[0];
  __syncthreads();
  float ex = expf(sc - mx);
  red[t] = ex;
  __syncthreads();
  for (int off = 128; off; off >>= 1) {
    if (t < off) red[t] += red[t + off];
    __syncthreads();
  }
  w[t] = ex / red[0];
  __syncthreads();
  float acc = 0.f;
  for (int k = 0; k < 256; k++)
    acc += w[k] * tok[(size_t)(b * 256 + k) * 256 + t];
  AO[b * 256 + t] = acc;
}

// ---------------- y = AOflat @ Wout + bout; out_row = y @ W3 + b3; tile 25 --
__global__ __launch_bounds__(256) void final_out_kernel(
    const float* __restrict__ AO, const float* __restrict__ Wout,
    const float* __restrict__ bout, const float* __restrict__ W3,
    const float* __restrict__ b3, float* __restrict__ out) {
  __shared__ float a[1280];
  __shared__ float y[256];
  int j = threadIdx.x;
  for (int i = j; i < 1280; i += 256) a[i] = AO[i];
  __syncthreads();
  float acc = bout[j];
  for (int k = 0; k < 1280; k++) acc += a[k] * Wout[k * 256 + j];
  y[j] = acc;
  __syncthreads();
  for (int q = 0; q < 4; q++) {
    int t = j + q * 256;
    float o = b3[t];
    for (int k = 0; k < 256; k++) o += y[k] * W3[k * 1024 + t];
    for (int g = 0; g < 25; g++) out[(size_t)g * 1024 + t] = o;
  }
}

extern "C" void kernel_launch(void* const* d_in, const int* in_sizes, int n_in,
                              void* d_out, int out_size, void* d_ws,
                              size_t ws_size, hipStream_t stream) {
  const int* concept_ids = (const int*)d_in[0];
  const int* edge_index = (const int*)d_in[1];
  const float* sent = (const float*)d_in[3];
  const float* tokemb = (const float*)d_in[4];
  const int* batch = (const int*)d_in[5];
  const float* ent = (const float*)d_in[6];
  const float* Wq = (const float*)d_in[7];
  const float* bq = (const float*)d_in[8];
  const float* Wk = (const float*)d_in[9];
  const float* bk = (const float*)d_in[10];
  const float* Wv = (const float*)d_in[11];
  const float* bv = (const float*)d_in[12];
  const float* Ws = (const float*)d_in[13];
  const float* bs = (const float*)d_in[14];
  const float* Wo = (const float*)d_in[15];
  const float* bo = (const float*)d_in[16];
  const float* W1 = (const float*)d_in[17];
  const float* b1 = (const float*)d_in[18];
  const float* W2 = (const float*)d_in[19];
  const float* b2 = (const float*)d_in[20];
  const float* W3 = (const float*)d_in[21];
  const float* b3 = (const float*)d_in[22];
  const float* Wout = (const float*)d_in[23];
  const float* bout = (const float*)d_in[24];
  float* out = (float*)d_out;

  float* ws = (float*)d_ws;
  size_t off_ = 0;
  auto alloc = [&](size_t n) {
    float* p = ws + off_;
    off_ += n;
    return p;
  };
  float* x = alloc((size_t)NNODES * DM);
  float* x2 = alloc((size_t)NNODES * DM);
  float* Qb = alloc((size_t)NNODES * DM);  // reused as agg after scores
  float* Kb = alloc((size_t)NNODES * DM);
  float* Vb = alloc((size_t)NNODES * DM);
  float* sExp = alloc((size_t)NEDGES * 4);
  float* tok = alloc(1280 * 256);
  float* QS5 = alloc(5 * 256);
  float* sums = alloc(4);
  float* agg0 = alloc(256);
  float* x1 = alloc(256);
  float* AO = alloc(1280);
  int* deg = (int*)alloc(NNODES);
  int* csr_off = (int*)alloc(NNODES + 1);
  int* cursor = (int*)alloc(NNODES);
  int* perm = (int*)alloc(NEDGES);
  int* colPerm = (int*)alloc(NEDGES);

  dim3 gblk(16, 16);

  // x = entity_embeddings[concept_ids]
  gather_kernel<<<(NNODES * 64 + 255) / 256, 256, 0, stream>>>(concept_ids, ent,
                                                               x, NNODES);

  // CSR build (edge structure is layer-invariant)
  hipMemsetAsync(deg, 0, NNODES * sizeof(int), stream);
  deg_kernel<<<(NEDGES + 255) / 256, 256, 0, stream>>>(edge_index, deg, NEDGES);
  scan_kernel<<<1, 256, 0, stream>>>(deg, csr_off, NNODES);
  hipMemcpyAsync(cursor, csr_off, NNODES * sizeof(int),
                 hipMemcpyDeviceToDevice, stream);
  fill_kernel<<<(NEDGES + 255) / 256, 256, 0, stream>>>(edge_index, cursor,
                                                        perm, colPerm, NEDGES);

  float* xin = x;
  float* xout = x2;
  for (int l = 0; l < 3; l++) {
    const float* Wql = Wq + (size_t)l * DM * DM;
    const float* Wkl = Wk + (size_t)l * DM * DM;
    const float* Wvl = Wv + (size_t)l * DM * DM;
    const float* Wsl = Ws + (size_t)l * 1024 * DM;
    const float* Wol = Wo + (size_t)l * DM * DM;

    dim3 grid(DM / 64, (NNODES + 63) / 64);
    gemm_f32_kernel<<<grid, gblk, 0, stream>>>(xin, Wql, bq + l * DM, nullptr,
                                               Qb, NNODES, DM, DM);
    gemm_f32_kernel<<<grid, gblk, 0, stream>>>(xin, Wkl, bk + l * DM, nullptr,
                                               Kb, NNODES, DM, DM);
    gemm_f32_kernel<<<grid, gblk, 0, stream>>>(xin, Wvl, bv + l * DM, nullptr,
                                               Vb, NNODES, DM, DM);
    qs5_kernel<<<5, 256, 0, stream>>>(sent, Wsl, bs + l * DM, QS5);

    hipMemsetAsync(sums, 0, 4 * sizeof(float), stream);
    edge_score_kernel<<<10000, 256, 0, stream>>>(edge_index, batch, Qb, Kb, QS5,
                                                 perm, sExp, sums, NEDGES);
    if (l < 2) {
      // agg aliases Qb (Q no longer needed); gather writes every element
      gather_agg_kernel<<<(NNODES * 64 + 255) / 256, 256, 0, stream>>>(
          csr_off, colPerm, sExp, sums, Vb, Qb, NNODES);
      gemm_f32_kernel<<<grid, gblk, 0, stream>>>(Qb, Wol, bo + l * DM, xin,
                                                 xout, NNODES, DM, DM);
      float* tmp = xin;
      xin = xout;
      xout = tmp;
    } else {
      // only agg[0] is needed downstream
      gather_agg_kernel<<<1, 256, 0, stream>>>(csr_off, colPerm, sExp, sums, Vb,
                                               agg0, 1);
      final_head_kernel<<<1, 256, 0, stream>>>(agg0, Wol, bo + 2 * DM, xin, W1,
                                               b1, x1);
    }
  }

  // tok = token_embedding(1280x1024) @ W2 + b2
  {
    dim3 grid(DM / 64, 1280 / 64);
    gemm_f32_kernel<<<grid, gblk, 0, stream>>>(tokemb, W2, b2, nullptr, tok,
                                               1280, DM, 1024);
  }
  attn_out_kernel<<<5, 256, 0, stream>>>(x1, tok, AO);
  final_out_kernel<<<1, 256, 0, stream>>>(AO, Wout, bout, W3, b3, out);
}

// Round 3
// 1275.248 us; speedup vs baseline: 4.5446x; 1.4670x over previous
//
#include <hip/hip_runtime.h>
#include <hip/hip_bf16.h>

#define NNODES 20000
#define NEDGES 640000
#define DM 256

typedef short s16x8 __attribute__((ext_vector_type(8)));
typedef float f32x4 __attribute__((ext_vector_type(4)));

__device__ inline float b2f(unsigned short u) {
  union { unsigned int i; float f; } z;
  z.i = (unsigned int)u << 16;
  return z.f;
}
__device__ inline unsigned short f2b(float f) {
  union { unsigned int i; float f; } z;
  z.f = f;
  unsigned int i = z.i;
  return (unsigned short)((i + 0x7FFFu + ((i >> 16) & 1u)) >> 16);
}

// ---------------- gather: x = ent[cid] (f32 + bf16) -------------------------
__global__ __launch_bounds__(256) void gather_kernel(
    const int* __restrict__ cid, const float* __restrict__ ent,
    float* __restrict__ x, unsigned short* __restrict__ xb, int n) {
  int idx = blockIdx.x * 256 + threadIdx.x;
  if (idx >= n * 64) return;
  int node = idx >> 6, d4 = idx & 63;
  float4 v = reinterpret_cast<const float4*>(ent)[(size_t)cid[node] * 64 + d4];
  reinterpret_cast<float4*>(x)[(size_t)node * 64 + d4] = v;
  ushort4 b;
  b.x = f2b(v.x); b.y = f2b(v.y); b.z = f2b(v.z); b.w = f2b(v.w);
  reinterpret_cast<ushort4*>(xb)[(size_t)node * 64 + d4] = b;
}

// ---------------- weight transpose -> bf16 [N][K] ---------------------------
__global__ __launch_bounds__(256) void wtrans_kernel(
    const float* __restrict__ W, unsigned short* __restrict__ Wt) {
  int i = blockIdx.x * 256 + threadIdx.x;  // 65536
  int n = i >> 8, k = i & 255;
  Wt[n * 256 + k] = f2b(W[k * 256 + n]);
}

// ---------------- MFMA bf16 GEMM: M x 256 x 256 -----------------------------
// A[M][256] bf16, Bt[256][256] bf16 (Bt[n][k] = B[k][n]). 64x64 block, 4 waves.
__global__ __launch_bounds__(256) void gemm_bf16_kernel(
    const unsigned short* __restrict__ A, const unsigned short* __restrict__ Bt,
    const float* __restrict__ bias, const float* __restrict__ resid,
    float* __restrict__ Cf, unsigned short* __restrict__ Cb, int M) {
  int wid = threadIdx.x >> 6;
  int lane = threadIdx.x & 63;
  int wr = wid >> 1, wc = wid & 1;
  int rowBase = blockIdx.y * 64 + wr * 32;
  int colBase = blockIdx.x * 64 + wc * 32;
  int r16 = lane & 15, kg = lane >> 4;
  f32x4 acc[2][2] = {};
  for (int k0 = 0; k0 < 256; k0 += 32) {
    s16x8 a[2], b[2];
#pragma unroll
    for (int mi = 0; mi < 2; mi++) {
      int r = rowBase + mi * 16 + r16;
      s16x8 z = {};
      a[mi] = (r < M) ? *reinterpret_cast<const s16x8*>(
                            &A[(size_t)r * 256 + k0 + kg * 8])
                      : z;
    }
#pragma unroll
    for (int ni = 0; ni < 2; ni++) {
      int c = colBase + ni * 16 + r16;
      b[ni] = *reinterpret_cast<const s16x8*>(&Bt[(size_t)c * 256 + k0 + kg * 8]);
    }
#pragma unroll
    for (int mi = 0; mi < 2; mi++)
#pragma unroll
      for (int ni = 0; ni < 2; ni++)
        acc[mi][ni] = __builtin_amdgcn_mfma_f32_16x16x32_bf16(a[mi], b[ni],
                                                              acc[mi][ni], 0, 0, 0);
  }
#pragma unroll
  for (int mi = 0; mi < 2; mi++)
#pragma unroll
    for (int ni = 0; ni < 2; ni++) {
      int c = colBase + ni * 16 + (lane & 15);
      float bia = bias[c];
#pragma unroll
      for (int reg = 0; reg < 4; reg++) {
        int r = rowBase + mi * 16 + (lane >> 4) * 4 + reg;
        if (r >= M) continue;
        float v = acc[mi][ni][reg] + bia;
        if (resid) v += resid[(size_t)r * 256 + c];
        if (Cf) Cf[(size_t)r * 256 + c] = v;
        if (Cb) Cb[(size_t)r * 256 + c] = f2b(v);
      }
    }
}

// ---------------- generic f32 GEMM (for tok) --------------------------------
__global__ __launch_bounds__(256) void gemm_f32_kernel(
    const float* __restrict__ A, const float* __restrict__ B,
    const float* __restrict__ bias, float* __restrict__ C, int M, int N,
    int K) {
  __shared__ float As[16][68];
  __shared__ float Bs[16][68];
  int tx = threadIdx.x, ty = threadIdx.y;
  int tid = ty * 16 + tx;
  int rowBase = blockIdx.y * 64;
  int colBase = blockIdx.x * 64;
  float acc[4][4] = {};
  for (int k0 = 0; k0 < K; k0 += 16) {
#pragma unroll
    for (int i = 0; i < 4; i++) {
      int idx = tid + i * 256;
      int m = idx >> 4, kk = idx & 15;
      int gr = rowBase + m;
      As[kk][m] = (gr < M) ? A[(size_t)gr * K + (k0 + kk)] : 0.f;
    }
#pragma unroll
    for (int i = 0; i < 4; i++) {
      int idx = tid + i * 256;
      int kk = idx >> 6, n = idx & 63;
      Bs[kk][n] = B[(size_t)(k0 + kk) * N + colBase + n];
    }
    __syncthreads();
#pragma unroll
    for (int kk = 0; kk < 16; kk++) {
      float a[4], b[4];
#pragma unroll
      for (int i = 0; i < 4; i++) a[i] = As[kk][ty * 4 + i];
#pragma unroll
      for (int j = 0; j < 4; j++) b[j] = Bs[kk][tx * 4 + j];
#pragma unroll
      for (int i = 0; i < 4; i++)
#pragma unroll
        for (int j = 0; j < 4; j++) acc[i][j] += a[i] * b[j];
    }
    __syncthreads();
  }
#pragma unroll
  for (int i = 0; i < 4; i++) {
    int r = rowBase + ty * 4 + i;
    if (r >= M) continue;
#pragma unroll
    for (int j = 0; j < 4; j++) {
      int c = colBase + tx * 4 + j;
      C[(size_t)r * N + c] = acc[i][j] + bias[c];
    }
  }
}

// ---------------- QS5 = sentence_embeddings @ Ws[l] + bs[l]  (5x256) --------
__global__ __launch_bounds__(256) void qs5_kernel(
    const float* __restrict__ sent, const float* __restrict__ Ws,
    const float* __restrict__ bs, float* __restrict__ QS5) {
  int g = blockIdx.x;
  int j = threadIdx.x;
  float acc = bs[j];
  for (int k = 0; k < 1024; k++) acc += sent[g * 1024 + k] * Ws[k * 256 + j];
  QS5[g * 256 + j] = acc;
}

// ---------------- CSR build ----------------
__global__ __launch_bounds__(256) void deg_kernel(const int* __restrict__ ei,
                                                  int* __restrict__ deg, int E) {
  int e = blockIdx.x * 256 + threadIdx.x;
  if (e < E) atomicAdd(&deg[ei[e]], 1);
}

__global__ __launch_bounds__(256) void scan_kernel(const int* __restrict__ deg,
                                                   int* __restrict__ off,
                                                   int n) {
  __shared__ int buf[256];
  __shared__ int carry;
  if (threadIdx.x == 0) carry = 0;
  __syncthreads();
  for (int base = 0; base < n; base += 256) {
    int i = base + threadIdx.x;
    int v = (i < n) ? deg[i] : 0;
    buf[threadIdx.x] = v;
    __syncthreads();
    for (int ofs = 1; ofs < 256; ofs <<= 1) {
      int t = (threadIdx.x >= ofs) ? buf[threadIdx.x - ofs] : 0;
      __syncthreads();
      buf[threadIdx.x] += t;
      __syncthreads();
    }
    if (i < n) off[i] = carry + buf[threadIdx.x] - v;
    __syncthreads();
    if (threadIdx.x == 255) carry += buf[255];
    __syncthreads();
  }
  if (threadIdx.x == 0) off[n] = carry;
}

// colPerm[pos] = col | (group(col) << 24)
__global__ __launch_bounds__(256) void fill_kernel(const int* __restrict__ ei,
                                                   const int* __restrict__ batch,
                                                   int* __restrict__ cursor,
                                                   int* __restrict__ colPerm,
                                                   int E) {
  int e = blockIdx.x * 256 + threadIdx.x;
  if (e >= E) return;
  int r = ei[e];
  int c = ei[E + e];
  int pos = atomicAdd(&cursor[r], 1);
  colPerm[pos] = c | ((batch[c] / 5) << 24);
}

// ---------------- fused edge pass (CSR order, wave per node) ----------------
// DO_AGG=1: accumulate unnormalized agg into aggU (f32) + global exp-sums.
// DO_AGG=0: sums only.
template <int DO_AGG>
__global__ __launch_bounds__(256) void fused_edge_kernel(
    const int* __restrict__ off, const int* __restrict__ colPerm,
    const int* __restrict__ batch, const float* __restrict__ Q,
    const unsigned short* __restrict__ Kb, const unsigned short* __restrict__ Vb,
    const float* __restrict__ QS5, float* __restrict__ sums,
    float* __restrict__ aggU, int n) {
  int node = (blockIdx.x * 256 + threadIdx.x) >> 6;
  int lane = threadIdx.x & 63;
  int head = lane >> 4;
  float sumExp = 0.f;
  float4 acc = {0.f, 0.f, 0.f, 0.f};
  float4 qe = {0.f, 0.f, 0.f, 0.f};
  float dq0 = 0.f, dq1 = 0.f, dq2 = 0.f, dq3 = 0.f, dq4 = 0.f;
  int s0 = 0, s1 = 0;
  if (node < n) {
    float4 q = reinterpret_cast<const float4*>(Q)[(size_t)node * 64 + lane];
    int gr = batch[node] / 5;
    float4 qs = reinterpret_cast<const float4*>(QS5)[gr * 64 + lane];
    qe.x = q.x + qs.x; qe.y = q.y + qs.y; qe.z = q.z + qs.z; qe.w = q.w + qs.w;
#pragma unroll
    for (int g = 0; g < 5; g++) {
      float4 w = reinterpret_cast<const float4*>(QS5)[g * 64 + lane];
      float d = q.x * w.x + q.y * w.y + q.z * w.z + q.w * w.w;
      d += __shfl_xor(d, 1);
      d += __shfl_xor(d, 2);
      d += __shfl_xor(d, 4);
      d += __shfl_xor(d, 8);
      if (g == 0) dq0 = d;
      else if (g == 1) dq1 = d;
      else if (g == 2) dq2 = d;
      else if (g == 3) dq3 = d;
      else dq4 = d;
    }
    s0 = off[node];
    s1 = off[node + 1];
  }
  for (int m = s0; m < s1; m++) {
    int cc = colPerm[m];
    int c = cc & 0xFFFFFF, gc = cc >> 24;
    ushort4 ku = reinterpret_cast<const ushort4*>(Kb)[(size_t)c * 64 + lane];
    float p = qe.x * b2f(ku.x) + qe.y * b2f(ku.y) + qe.z * b2f(ku.z) +
              qe.w * b2f(ku.w);
    p += __shfl_xor(p, 1);
    p += __shfl_xor(p, 2);
    p += __shfl_xor(p, 4);
    p += __shfl_xor(p, 8);
    float dqv = (gc == 0) ? dq0
                : (gc == 1) ? dq1
                : (gc == 2) ? dq2
                : (gc == 3) ? dq3 : dq4;
    float v = (p + dqv) * (1.f / 24.f);
    v = (v >= 0.f) ? v : 0.2f * v;
    float ev = __expf(v);
    if ((lane & 15) == 0) sumExp += ev;
    if (DO_AGG) {
      ushort4 vu = reinterpret_cast<const ushort4*>(Vb)[(size_t)c * 64 + lane];
      acc.x += ev * b2f(vu.x);
      acc.y += ev * b2f(vu.y);
      acc.z += ev * b2f(vu.z);
      acc.w += ev * b2f(vu.w);
    }
  }
  if (DO_AGG && node < n)
    reinterpret_cast<float4*>(aggU)[(size_t)node * 64 + lane] = acc;
  __shared__ float red[4][4];
  int w = threadIdx.x >> 6;
  if ((lane & 15) == 0) red[w][head] = sumExp;
  __syncthreads();
  if (threadIdx.x < 4) {
    float t = red[0][threadIdx.x] + red[1][threadIdx.x] + red[2][threadIdx.x] +
              red[3][threadIdx.x];
    atomicAdd(&sums[threadIdx.x], t);
  }
}

// ---------------- normalize: aggb = bf16(aggU / sums[head]) -----------------
__global__ __launch_bounds__(256) void normalize_kernel(
    const float* __restrict__ aggU, const float* __restrict__ sums,
    unsigned short* __restrict__ aggb, int n) {
  int i = blockIdx.x * 256 + threadIdx.x;
  if (i >= n * 64) return;
  int head = (i & 63) >> 4;
  float invS = 1.f / sums[head];
  float4 u = reinterpret_cast<const float4*>(aggU)[i];
  ushort4 b;
  b.x = f2b(u.x * invS);
  b.y = f2b(u.y * invS);
  b.z = f2b(u.z * invS);
  b.w = f2b(u.w * invS);
  reinterpret_cast<ushort4*>(aggb)[i] = b;
}

// ---------------- layer-2: agg for node 0 only ------------------------------
__global__ __launch_bounds__(64) void node0_agg_kernel(
    const int* __restrict__ off, const int* __restrict__ colPerm,
    const int* __restrict__ batch, const float* __restrict__ Q,
    const unsigned short* __restrict__ Kb, const unsigned short* __restrict__ Vb,
    const float* __restrict__ QS5, const float* __restrict__ sums,
    float* __restrict__ agg0) {
  int lane = threadIdx.x;
  int head = lane >> 4;
  float4 q = reinterpret_cast<const float4*>(Q)[lane];
  int gr = batch[0] / 5;
  float4 qs = reinterpret_cast<const float4*>(QS5)[gr * 64 + lane];
  float4 qe = {q.x + qs.x, q.y + qs.y, q.z + qs.z, q.w + qs.w};
  float dq0 = 0.f, dq1 = 0.f, dq2 = 0.f, dq3 = 0.f, dq4 = 0.f;
#pragma unroll
  for (int g = 0; g < 5; g++) {
    float4 w = reinterpret_cast<const float4*>(QS5)[g * 64 + lane];
    float d = q.x * w.x + q.y * w.y + q.z * w.z + q.w * w.w;
    d += __shfl_xor(d, 1);
    d += __shfl_xor(d, 2);
    d += __shfl_xor(d, 4);
    d += __shfl_xor(d, 8);
    if (g == 0) dq0 = d;
    else if (g == 1) dq1 = d;
    else if (g == 2) dq2 = d;
    else if (g == 3) dq3 = d;
    else dq4 = d;
  }
  float4 acc = {0.f, 0.f, 0.f, 0.f};
  for (int m = off[0]; m < off[1]; m++) {
    int cc = colPerm[m];
    int c = cc & 0xFFFFFF, gc = cc >> 24;
    ushort4 ku = reinterpret_cast<const ushort4*>(Kb)[(size_t)c * 64 + lane];
    float p = qe.x * b2f(ku.x) + qe.y * b2f(ku.y) + qe.z * b2f(ku.z) +
              qe.w * b2f(ku.w);
    p += __shfl_xor(p, 1);
    p += __shfl_xor(p, 2);
    p += __shfl_xor(p, 4);
    p += __shfl_xor(p, 8);
    float dqv = (gc == 0) ? dq0
                : (gc == 1) ? dq1
                : (gc == 2) ? dq2
                : (gc == 3) ? dq3 : dq4;
    float v = (p + dqv) * (1.f / 24.f);
    v = (v >= 0.f) ? v : 0.2f * v;
    float ev = __expf(v);
    ushort4 vu = reinterpret_cast<const ushort4*>(Vb)[(size_t)c * 64 + lane];
    acc.x += ev * b2f(vu.x);
    acc.y += ev * b2f(vu.y);
    acc.z += ev * b2f(vu.z);
    acc.w += ev * b2f(vu.w);
  }
  float invS = 1.f / sums[head];
  acc.x *= invS; acc.y *= invS; acc.z *= invS; acc.w *= invS;
  reinterpret_cast<float4*>(agg0)[lane] = acc;
}

// x1 = ((agg0 @ Wo2 + bo2 + x[0]) @ W1 + b1)
__global__ __launch_bounds__(256) void final_head_kernel(
    const float* __restrict__ agg0, const float* __restrict__ Wo2,
    const float* __restrict__ bo2, const float* __restrict__ x,
    const float* __restrict__ W1, const float* __restrict__ b1,
    float* __restrict__ x1) {
  __shared__ float a0[256];
  __shared__ float t1[256];
  int j = threadIdx.x;
  a0[j] = agg0[j];
  __syncthreads();
  float acc = bo2[j] + x[j];
  for (int k = 0; k < 256; k++) acc += a0[k] * Wo2[k * 256 + j];
  t1[j] = acc;
  __syncthreads();
  float acc2 = b1[j];
  for (int k = 0; k < 256; k++) acc2 += t1[k] * W1[k * 256 + j];
  x1[j] = acc2;
}

// ---------------- AO[b] = softmax_t(x1 . tok[b,t] / 16) @ tok[b] ------------
__global__ __launch_bounds__(256) void attn_out_kernel(
    const float* __restrict__ x1g, const float* __restrict__ tok,
    float* __restrict__ AO) {
  int b = blockIdx.x;
  int t = threadIdx.x;
  __shared__ float x1[256];
  __shared__ float w[256];
  __shared__ float red[256];
  x1[t] = x1g[t];
  __syncthreads();
  const float* tr = tok + (size_t)(b * 256 + t) * 256;
  float sc = 0.f;
  for (int d = 0; d < 256; d++) sc += x1[d] * tr[d];
  sc *= (1.f / 16.f);
  red[t] = sc;
  __syncthreads();
  for (int off = 128; off; off >>= 1) {
    if (t < off) red[t] = fmaxf(red[t], red[t + off]);
    __syncthreads();
  }
  float mx = red[0];
  __syncthreads();
  float ex = expf(sc - mx);
  red[t] = ex;
  __syncthreads();
  for (int off = 128; off; off >>= 1) {
    if (t < off) red[t] += red[t + off];
    __syncthreads();
  }
  w[t] = ex / red[0];
  __syncthreads();
  float acc = 0.f;
  for (int k = 0; k < 256; k++)
    acc += w[k] * tok[(size_t)(b * 256 + k) * 256 + t];
  AO[b * 256 + t] = acc;
}

// ---------------- y = AOflat @ Wout + bout; out_row = y @ W3 + b3; tile 25 --
__global__ __launch_bounds__(256) void final_out_kernel(
    const float* __restrict__ AO, const float* __restrict__ Wout,
    const float* __restrict__ bout, const float* __restrict__ W3,
    const float* __restrict__ b3, float* __restrict__ out) {
  __shared__ float a[1280];
  __shared__ float y[256];
  int j = threadIdx.x;
  for (int i = j; i < 1280; i += 256) a[i] = AO[i];
  __syncthreads();
  float acc = bout[j];
  for (int k = 0; k < 1280; k++) acc += a[k] * Wout[k * 256 + j];
  y[j] = acc;
  __syncthreads();
  for (int q = 0; q < 4; q++) {
    int t = j + q * 256;
    float o = b3[t];
    for (int k = 0; k < 256; k++) o += y[k] * W3[k * 1024 + t];
    for (int g = 0; g < 25; g++) out[(size_t)g * 1024 + t] = o;
  }
}

extern "C" void kernel_launch(void* const* d_in, const int* in_sizes, int n_in,
                              void* d_out, int out_size, void* d_ws,
                              size_t ws_size, hipStream_t stream) {
  const int* concept_ids = (const int*)d_in[0];
  const int* edge_index = (const int*)d_in[1];
  const float* sent = (const float*)d_in[3];
  const float* tokemb = (const float*)d_in[4];
  const int* batch = (const int*)d_in[5];
  const float* ent = (const float*)d_in[6];
  const float* Wq = (const float*)d_in[7];
  const float* bq = (const float*)d_in[8];
  const float* Wk = (const float*)d_in[9];
  const float* bk = (const float*)d_in[10];
  const float* Wv = (const float*)d_in[11];
  const float* bv = (const float*)d_in[12];
  const float* Ws = (const float*)d_in[13];
  const float* bs = (const float*)d_in[14];
  const float* Wo = (const float*)d_in[15];
  const float* bo = (const float*)d_in[16];
  const float* W1 = (const float*)d_in[17];
  const float* b1 = (const float*)d_in[18];
  const float* W2 = (const float*)d_in[19];
  const float* b2 = (const float*)d_in[20];
  const float* W3 = (const float*)d_in[21];
  const float* b3 = (const float*)d_in[22];
  const float* Wout = (const float*)d_in[23];
  const float* bout = (const float*)d_in[24];
  float* out = (float*)d_out;

  float* ws = (float*)d_ws;
  size_t off_ = 0;
  auto alloc = [&](size_t n) {
    float* p = ws + off_;
    off_ += n;
    return p;
  };
  float* x = alloc((size_t)NNODES * DM);        // f32 x
  float* x2 = alloc((size_t)NNODES * DM);       // f32 x ping-pong
  float* Qf = alloc((size_t)NNODES * DM);       // Q f32; reused as unnorm agg
  unsigned short* xb = (unsigned short*)alloc((size_t)NNODES * DM / 2);
  unsigned short* aggb = (unsigned short*)alloc((size_t)NNODES * DM / 2);
  unsigned short* Kb = (unsigned short*)alloc((size_t)NNODES * DM / 2);
  unsigned short* Vb = (unsigned short*)alloc((size_t)NNODES * DM / 2);
  unsigned short* WT = (unsigned short*)alloc(12 * 65536 / 2);
  float* tok = alloc(1280 * 256);
  float* QS5 = alloc(5 * 256);
  float* sums = alloc(4);
  float* agg0 = alloc(256);
  float* x1 = alloc(256);
  float* AO = alloc(1280);
  int* deg = (int*)alloc(NNODES);
  int* cursor = (int*)alloc(NNODES);
  int* colPerm = (int*)alloc(NEDGES);
  int* csr_off = (int*)alloc(NNODES + 1);

  dim3 gblk(16, 16);

  // x = entity_embeddings[concept_ids] (f32 + bf16)
  gather_kernel<<<(NNODES * 64 + 255) / 256, 256, 0, stream>>>(
      concept_ids, ent, x, xb, NNODES);

  // weight transposes -> bf16 [N][K]: Wq/Wk/Wv/Wo per layer
  for (int l = 0; l < 3; l++) {
    wtrans_kernel<<<256, 256, 0, stream>>>(Wq + (size_t)l * 65536,
                                           WT + (size_t)(l * 4 + 0) * 65536);
    wtrans_kernel<<<256, 256, 0, stream>>>(Wk + (size_t)l * 65536,
                                           WT + (size_t)(l * 4 + 1) * 65536);
    wtrans_kernel<<<256, 256, 0, stream>>>(Wv + (size_t)l * 65536,
                                           WT + (size_t)(l * 4 + 2) * 65536);
    wtrans_kernel<<<256, 256, 0, stream>>>(Wo + (size_t)l * 65536,
                                           WT + (size_t)(l * 4 + 3) * 65536);
  }

  // CSR build (edge structure is layer-invariant)
  hipMemsetAsync(deg, 0, NNODES * sizeof(int), stream);
  deg_kernel<<<(NEDGES + 255) / 256, 256, 0, stream>>>(edge_index, deg, NEDGES);
  scan_kernel<<<1, 256, 0, stream>>>(deg, csr_off, NNODES);
  hipMemcpyAsync(cursor, csr_off, NNODES * sizeof(int),
                 hipMemcpyDeviceToDevice, stream);
  fill_kernel<<<(NEDGES + 255) / 256, 256, 0, stream>>>(edge_index, batch,
                                                        cursor, colPerm, NEDGES);

  float* xin = x;
  float* xout = x2;
  dim3 ggrid(4, (NNODES + 63) / 64);
  for (int l = 0; l < 3; l++) {
    const unsigned short* WqT = WT + (size_t)(l * 4 + 0) * 65536;
    const unsigned short* WkT = WT + (size_t)(l * 4 + 1) * 65536;
    const unsigned short* WvT = WT + (size_t)(l * 4 + 2) * 65536;
    const unsigned short* WoT = WT + (size_t)(l * 4 + 3) * 65536;

    gemm_bf16_kernel<<<ggrid, 256, 0, stream>>>(xb, WqT, bq + l * DM, nullptr,
                                                Qf, nullptr, NNODES);
    gemm_bf16_kernel<<<ggrid, 256, 0, stream>>>(xb, WkT, bk + l * DM, nullptr,
                                                nullptr, Kb, NNODES);
    gemm_bf16_kernel<<<ggrid, 256, 0, stream>>>(xb, WvT, bv + l * DM, nullptr,
                                                nullptr, Vb, NNODES);
    qs5_kernel<<<5, 256, 0, stream>>>(sent, Ws + (size_t)l * 1024 * DM,
                                      bs + l * DM, QS5);
    hipMemsetAsync(sums, 0, 4 * sizeof(float), stream);
    if (l < 2) {
      fused_edge_kernel<1><<<(NNODES * 64 + 255) / 256, 256, 0, stream>>>(
          csr_off, colPerm, batch, Qf, Kb, Vb, QS5, sums, Qf, NNODES);
      normalize_kernel<<<(NNODES * 64 + 255) / 256, 256, 0, stream>>>(
          Qf, sums, aggb, NNODES);
      gemm_bf16_kernel<<<ggrid, 256, 0, stream>>>(aggb, WoT, bo + l * DM, xin,
                                                  xout, xb, NNODES);
      float* tmp = xin;
      xin = xout;
      xout = tmp;
    } else {
      fused_edge_kernel<0><<<(NNODES * 64 + 255) / 256, 256, 0, stream>>>(
          csr_off, colPerm, batch, Qf, Kb, Vb, QS5, sums, nullptr, NNODES);
      node0_agg_kernel<<<1, 64, 0, stream>>>(csr_off, colPerm, batch, Qf, Kb,
                                             Vb, QS5, sums, agg0);
      final_head_kernel<<<1, 256, 0, stream>>>(agg0, Wo + (size_t)2 * 65536,
                                               bo + 2 * DM, xin, W1, b1, x1);
    }
  }

  // tok = token_embedding(1280x1024) @ W2 + b2 (f32)
  {
    dim3 grid(DM / 64, 1280 / 64);
    gemm_f32_kernel<<<grid, gblk, 0, stream>>>(tokemb, W2, b2, tok, 1280, DM,
                                               1024);
  }
  attn_out_kernel<<<5, 256, 0, stream>>>(x1, tok, AO);
  final_out_kernel<<<1, 256, 0, stream>>>(AO, Wout, bout, W3, b3, out);
}

// Round 4
// 846.451 us; speedup vs baseline: 6.8468x; 1.5066x over previous
//
#include <hip/hip_runtime.h>
#include <hip/hip_bf16.h>

#define NNODES 20000
#define NEDGES 640000
#define DM 256
#define PAD 128

typedef short s16x8 __attribute__((ext_vector_type(8)));
typedef float f32x4 __attribute__((ext_vector_type(4)));
typedef float f32x2 __attribute__((ext_vector_type(2)));

__device__ inline float b2f(unsigned short u) {
  union { unsigned int i; float f; } z;
  z.i = (unsigned int)u << 16;
  return z.f;
}
__device__ inline unsigned short f2b(float f) {
  union { unsigned int i; float f; } z;
  z.f = f;
  unsigned int i = z.i;
  return (unsigned short)((i + 0x7FFFu + ((i >> 16) & 1u)) >> 16);
}

// ---------------- fp8 e4m3 encode/decode ------------------------------------
__device__ inline unsigned char f2fp8(float v) {
#if __has_builtin(__builtin_amdgcn_cvt_pk_fp8_f32)
  int t = __builtin_amdgcn_cvt_pk_fp8_f32(v, v, 0, false);
  return (unsigned char)(t & 0xFF);
#else
  union { float f; unsigned int u; } z;
  z.f = v;
  unsigned int s = (z.u >> 31) << 7;
  float av = fabsf(v);
  if (av >= 448.f) return (unsigned char)(s | 0x7E);
  if (av < 0.015625f) {
    int q = (int)rintf(av * 512.f);
    return (unsigned char)(s | (unsigned)q);
  }
  int e32 = (int)((z.u >> 23) & 255) - 127;
  unsigned mant = z.u & 0x7FFFFF;
  unsigned t = mant + 0x7FFFF + ((mant >> 20) & 1);
  if (t >= 0x800000u) { t = 0; e32++; }
  int e4 = e32 + 7;
  unsigned m3 = (t >> 20) & 7;
  if (e4 > 15 || (e4 == 15 && m3 == 7)) return (unsigned char)(s | 0x7E);
  return (unsigned char)(s | (unsigned)((e4 << 3) | m3));
#endif
}

__device__ inline float4 fp8x4_dec(unsigned int u) {
#if __has_builtin(__builtin_amdgcn_cvt_pk_f32_fp8)
  f32x2 lo = __builtin_amdgcn_cvt_pk_f32_fp8((int)u, false);
  f32x2 hi = __builtin_amdgcn_cvt_pk_f32_fp8((int)u, true);
  float4 r;
  r.x = lo[0]; r.y = lo[1]; r.z = hi[0]; r.w = hi[1];
  return r;
#else
  float4 r;
  float* p = &r.x;
#pragma unroll
  for (int j = 0; j < 4; j++) {
    unsigned b = (u >> (8 * j)) & 0xFF;
    unsigned s = b >> 7, e = (b >> 3) & 15, m = b & 7;
    float mag;
    if (e == 0) mag = (float)m * 0.001953125f;
    else {
      union { unsigned int i; float f; } z;
      z.i = ((e + 120u) << 23) | (m << 20);
      mag = z.f;
    }
    p[j] = s ? -mag : mag;
  }
  return r;
#endif
}

// ---------------- gather: x = ent[cid] (f32 + bf16) -------------------------
__global__ __launch_bounds__(256) void gather_kernel(
    const int* __restrict__ cid, const float* __restrict__ ent,
    float* __restrict__ x, unsigned short* __restrict__ xb, int n) {
  int idx = blockIdx.x * 256 + threadIdx.x;
  if (idx >= n * 64) return;
  int node = idx >> 6, d4 = idx & 63;
  float4 v = reinterpret_cast<const float4*>(ent)[(size_t)cid[node] * 64 + d4];
  reinterpret_cast<float4*>(x)[(size_t)node * 64 + d4] = v;
  ushort4 b;
  b.x = f2b(v.x); b.y = f2b(v.y); b.z = f2b(v.z); b.w = f2b(v.w);
  reinterpret_cast<ushort4*>(xb)[(size_t)node * 64 + d4] = b;
}

// ---------------- all 12 square weights -> bf16 [N][K] ----------------------
__global__ __launch_bounds__(256) void wtrans12_kernel(
    const float* __restrict__ Wq, const float* __restrict__ Wk,
    const float* __restrict__ Wv, const float* __restrict__ Wo,
    unsigned short* __restrict__ WT) {
  int slot = blockIdx.x >> 8;           // 0..11 = l*4 + t
  int l = slot >> 2, t = slot & 3;
  int n = blockIdx.x & 255;
  int k = threadIdx.x;
  const float* src = (t == 0) ? Wq : (t == 1) ? Wk : (t == 2) ? Wv : Wo;
  WT[(size_t)slot * 65536 + n * 256 + k] =
      f2b(src[(size_t)l * 65536 + k * 256 + n]);
}

// ---------------- W2 (1024x256) -> bf16 [256][1024] --------------------------
__global__ __launch_bounds__(256) void w2t_kernel(const float* __restrict__ W2,
                                                  unsigned short* __restrict__ W2T) {
  int i = blockIdx.x * 256 + threadIdx.x;  // 262144
  int n = i >> 10, k = i & 1023;
  W2T[n * 1024 + k] = f2b(W2[k * 256 + n]);
}

// ---------------- token_embedding f32 -> bf16 --------------------------------
__global__ __launch_bounds__(256) void tokconv_kernel(
    const float* __restrict__ te, unsigned short* __restrict__ tb) {
  int i = blockIdx.x * 256 + threadIdx.x;  // 327680 float4s
  float4 v = reinterpret_cast<const float4*>(te)[i];
  ushort4 b;
  b.x = f2b(v.x); b.y = f2b(v.y); b.z = f2b(v.z); b.w = f2b(v.w);
  reinterpret_cast<ushort4*>(tb)[i] = b;
}

// ---------------- padded-CSR fill: slot = atomicAdd(deg) --------------------
__global__ __launch_bounds__(256) void fill_kernel(const int* __restrict__ ei,
                                                   const int* __restrict__ batch,
                                                   int* __restrict__ deg,
                                                   int* __restrict__ colPad,
                                                   int E) {
  int e = blockIdx.x * 256 + threadIdx.x;
  if (e >= E) return;
  int r = ei[e];
  int c = ei[E + e];
  int slot = atomicAdd(&deg[r], 1);
  if (slot < PAD) colPad[(size_t)r * PAD + slot] = c | ((batch[c] / 5) << 24);
}

// ---------------- QS for all layers: QS5all[l][g][256] ----------------------
__global__ __launch_bounds__(256) void qs5all_kernel(
    const float* __restrict__ sent, const float* __restrict__ Ws,
    const float* __restrict__ bs, float* __restrict__ QS5all) {
  int g = blockIdx.x, l = blockIdx.y;
  int j = threadIdx.x;
  __shared__ float sh[1024];
  for (int i = j; i < 1024; i += 256) sh[i] = sent[g * 1024 + i];
  __syncthreads();
  const float* W = Ws + (size_t)l * 1024 * 256;
  float acc = bs[l * 256 + j];
  for (int k = 0; k < 1024; k++) acc += sh[k] * W[k * 256 + j];
  QS5all[(size_t)(l * 5 + g) * 256 + j] = acc;
}

// ---------------- fused QKV MFMA GEMM: [M,256] @ [256,768] ------------------
// Bt rows 0..255 = WqT, 256..511 = WkT, 512..767 = WvT (contiguous in WT).
// Region 0 -> Qf (f32); region 1 -> K8 (fp8); region 2 -> V8 (fp8).
__global__ __launch_bounds__(256) void qkv_gemm_kernel(
    const unsigned short* __restrict__ A, const unsigned short* __restrict__ Bt,
    const float* __restrict__ bq, const float* __restrict__ bk,
    const float* __restrict__ bv, float* __restrict__ Qf,
    unsigned char* __restrict__ K8, unsigned char* __restrict__ V8, int M) {
  int wid = threadIdx.x >> 6;
  int lane = threadIdx.x & 63;
  int wr = wid >> 1, wc = wid & 1;
  int rowBase = blockIdx.y * 64 + wr * 32;
  int colBase = blockIdx.x * 64 + wc * 32;  // 0..767
  int r16 = lane & 15, kg = lane >> 4;
  f32x4 acc[2][2] = {};
  for (int k0 = 0; k0 < 256; k0 += 32) {
    s16x8 a[2], b[2];
#pragma unroll
    for (int mi = 0; mi < 2; mi++) {
      int r = rowBase + mi * 16 + r16;
      s16x8 z = {};
      a[mi] = (r < M) ? *reinterpret_cast<const s16x8*>(
                            &A[(size_t)r * 256 + k0 + kg * 8])
                      : z;
    }
#pragma unroll
    for (int ni = 0; ni < 2; ni++) {
      int c = colBase + ni * 16 + r16;
      b[ni] = *reinterpret_cast<const s16x8*>(&Bt[(size_t)c * 256 + k0 + kg * 8]);
    }
#pragma unroll
    for (int mi = 0; mi < 2; mi++)
#pragma unroll
      for (int ni = 0; ni < 2; ni++)
        acc[mi][ni] = __builtin_amdgcn_mfma_f32_16x16x32_bf16(
            a[mi], b[ni], acc[mi][ni], 0, 0, 0);
  }
  int region = (blockIdx.x * 64) >> 8;  // 0,1,2 (block never straddles)
  const float* bias = (region == 0) ? bq : (region == 1) ? bk : bv;
  unsigned char* dst8 = (region == 1) ? K8 : V8;
#pragma unroll
  for (int mi = 0; mi < 2; mi++)
#pragma unroll
    for (int ni = 0; ni < 2; ni++) {
      int cg = colBase + ni * 16 + (lane & 15);
      int cr = cg & 255;
      float bia = bias[cr];
#pragma unroll
      for (int reg = 0; reg < 4; reg++) {
        int r = rowBase + mi * 16 + (lane >> 4) * 4 + reg;
        if (r >= M) continue;
        float v = acc[mi][ni][reg] + bia;
        if (region == 0)
          Qf[(size_t)r * 256 + cr] = v;
        else
          dst8[(size_t)r * 256 + cr] = f2fp8(v);
      }
    }
}

// ---------------- generic MFMA GEMM: C = A@Bt^T + bias (+resid) -------------
__global__ __launch_bounds__(256) void gemm_bf16_kernel(
    const unsigned short* __restrict__ A, const unsigned short* __restrict__ Bt,
    const float* __restrict__ bias, const float* __restrict__ resid,
    float* __restrict__ Cf, unsigned short* __restrict__ Cb, int M, int K) {
  int wid = threadIdx.x >> 6;
  int lane = threadIdx.x & 63;
  int wr = wid >> 1, wc = wid & 1;
  int rowBase = blockIdx.y * 64 + wr * 32;
  int colBase = blockIdx.x * 64 + wc * 32;
  int r16 = lane & 15, kg = lane >> 4;
  f32x4 acc[2][2] = {};
  for (int k0 = 0; k0 < K; k0 += 32) {
    s16x8 a[2], b[2];
#pragma unroll
    for (int mi = 0; mi < 2; mi++) {
      int r = rowBase + mi * 16 + r16;
      s16x8 z = {};
      a[mi] = (r < M) ? *reinterpret_cast<const s16x8*>(
                            &A[(size_t)r * K + k0 + kg * 8])
                      : z;
    }
#pragma unroll
    for (int ni = 0; ni < 2; ni++) {
      int c = colBase + ni * 16 + r16;
      b[ni] = *reinterpret_cast<const s16x8*>(&Bt[(size_t)c * K + k0 + kg * 8]);
    }
#pragma unroll
    for (int mi = 0; mi < 2; mi++)
#pragma unroll
      for (int ni = 0; ni < 2; ni++)
        acc[mi][ni] = __builtin_amdgcn_mfma_f32_16x16x32_bf16(
            a[mi], b[ni], acc[mi][ni], 0, 0, 0);
  }
#pragma unroll
  for (int mi = 0; mi < 2; mi++)
#pragma unroll
    for (int ni = 0; ni < 2; ni++) {
      int c = colBase + ni * 16 + (lane & 15);
      float bia = bias[c];
#pragma unroll
      for (int reg = 0; reg < 4; reg++) {
        int r = rowBase + mi * 16 + (lane >> 4) * 4 + reg;
        if (r >= M) continue;
        float v = acc[mi][ni][reg] + bia;
        if (resid) v += resid[(size_t)r * 256 + c];
        if (Cf) Cf[(size_t)r * 256 + c] = v;
        if (Cb) Cb[(size_t)r * 256 + c] = f2b(v);
      }
    }
}

// ---------------- rescale WoT rows by 1/sums[head] (fold softmax norm) ------
__global__ __launch_bounds__(256) void rescale_wo_kernel(
    unsigned short* __restrict__ WoT, const float* __restrict__ sums) {
  int i = blockIdx.x * 256 + threadIdx.x;  // 65536
  int head = (i & 255) >> 6;
  WoT[i] = f2b(b2f(WoT[i]) / sums[head]);
}

// ---------------- fused edge pass (padded CSR, wave per node) ----------------
// fp8 K/V. DO_AGG=1: write UNNORMALIZED agg (bf16) + global exp-sums.
template <int DO_AGG>
__global__ __launch_bounds__(256) void fused_edge_kernel(
    const int* __restrict__ deg, const int* __restrict__ colPad,
    const int* __restrict__ batch, const float* __restrict__ Q,
    const unsigned int* __restrict__ K8, const unsigned int* __restrict__ V8,
    const float* __restrict__ QS5, float* __restrict__ sums,
    unsigned short* __restrict__ aggb, int n) {
  int node = (blockIdx.x * 256 + threadIdx.x) >> 6;
  int lane = threadIdx.x & 63;
  int head = lane >> 4;
  float sumExp = 0.f;
  float4 acc = {0.f, 0.f, 0.f, 0.f};
  float4 qe = {0.f, 0.f, 0.f, 0.f};
  float dq0 = 0.f, dq1 = 0.f, dq2 = 0.f, dq3 = 0.f, dq4 = 0.f;
  int dcount = 0;
  if (node < n) {
    float4 q = reinterpret_cast<const float4*>(Q)[(size_t)node * 64 + lane];
    int gr = batch[node] / 5;
    float4 qs = reinterpret_cast<const float4*>(QS5)[gr * 64 + lane];
    qe.x = q.x + qs.x; qe.y = q.y + qs.y; qe.z = q.z + qs.z; qe.w = q.w + qs.w;
#pragma unroll
    for (int g = 0; g < 5; g++) {
      float4 w = reinterpret_cast<const float4*>(QS5)[g * 64 + lane];
      float d = q.x * w.x + q.y * w.y + q.z * w.z + q.w * w.w;
      d += __shfl_xor(d, 1);
      d += __shfl_xor(d, 2);
      d += __shfl_xor(d, 4);
      d += __shfl_xor(d, 8);
      if (g == 0) dq0 = d;
      else if (g == 1) dq1 = d;
      else if (g == 2) dq2 = d;
      else if (g == 3) dq3 = d;
      else dq4 = d;
    }
    dcount = deg[node];
    if (dcount > PAD) dcount = PAD;
  }
  const int* myCol = colPad + (size_t)node * PAD;
  for (int m = 0; m < dcount; m++) {
    int cc = myCol[m];
    int c = cc & 0xFFFFFF, gc = cc >> 24;
    float4 kd = fp8x4_dec(K8[(size_t)c * 64 + lane]);
    float p = qe.x * kd.x + qe.y * kd.y + qe.z * kd.z + qe.w * kd.w;
    p += __shfl_xor(p, 1);
    p += __shfl_xor(p, 2);
    p += __shfl_xor(p, 4);
    p += __shfl_xor(p, 8);
    float dqv = (gc == 0) ? dq0
                : (gc == 1) ? dq1
                : (gc == 2) ? dq2
                : (gc == 3) ? dq3 : dq4;
    float v = (p + dqv) * (1.f / 24.f);
    v = (v >= 0.f) ? v : 0.2f * v;
    float ev = __expf(v);
    if ((lane & 15) == 0) sumExp += ev;
    if (DO_AGG) {
      float4 vd = fp8x4_dec(V8[(size_t)c * 64 + lane]);
      acc.x += ev * vd.x;
      acc.y += ev * vd.y;
      acc.z += ev * vd.z;
      acc.w += ev * vd.w;
    }
  }
  if (DO_AGG && node < n) {
    ushort4 b;
    b.x = f2b(acc.x); b.y = f2b(acc.y); b.z = f2b(acc.z); b.w = f2b(acc.w);
    reinterpret_cast<ushort4*>(aggb)[(size_t)node * 64 + lane] = b;
  }
  __shared__ float red[4][4];
  int w = threadIdx.x >> 6;
  if ((lane & 15) == 0) red[w][head] = sumExp;
  __syncthreads();
  if (threadIdx.x < 4) {
    float t = red[0][threadIdx.x] + red[1][threadIdx.x] + red[2][threadIdx.x] +
              red[3][threadIdx.x];
    atomicAdd(&sums[threadIdx.x], t);
  }
}

// ---------------- layer-2: agg for node 0 only ------------------------------
__global__ __launch_bounds__(64) void node0_agg_kernel(
    const int* __restrict__ deg, const int* __restrict__ colPad,
    const int* __restrict__ batch, const float* __restrict__ Q,
    const unsigned int* __restrict__ K8, const unsigned int* __restrict__ V8,
    const float* __restrict__ QS5, const float* __restrict__ sums,
    float* __restrict__ agg0) {
  int lane = threadIdx.x;
  int head = lane >> 4;
  float4 q = reinterpret_cast<const float4*>(Q)[lane];
  int gr = batch[0] / 5;
  float4 qs = reinterpret_cast<const float4*>(QS5)[gr * 64 + lane];
  float4 qe = {q.x + qs.x, q.y + qs.y, q.z + qs.z, q.w + qs.w};
  float dq0 = 0.f, dq1 = 0.f, dq2 = 0.f, dq3 = 0.f, dq4 = 0.f;
#pragma unroll
  for (int g = 0; g < 5; g++) {
    float4 w = reinterpret_cast<const float4*>(QS5)[g * 64 + lane];
    float d = q.x * w.x + q.y * w.y + q.z * w.z + q.w * w.w;
    d += __shfl_xor(d, 1);
    d += __shfl_xor(d, 2);
    d += __shfl_xor(d, 4);
    d += __shfl_xor(d, 8);
    if (g == 0) dq0 = d;
    else if (g == 1) dq1 = d;
    else if (g == 2) dq2 = d;
    else if (g == 3) dq3 = d;
    else dq4 = d;
  }
  float4 acc = {0.f, 0.f, 0.f, 0.f};
  int dcount = deg[0];
  if (dcount > PAD) dcount = PAD;
  for (int m = 0; m < dcount; m++) {
    int cc = colPad[m];
    int c = cc & 0xFFFFFF, gc = cc >> 24;
    float4 kd = fp8x4_dec(K8[(size_t)c * 64 + lane]);
    float p = qe.x * kd.x + qe.y * kd.y + qe.z * kd.z + qe.w * kd.w;
    p += __shfl_xor(p, 1);
    p += __shfl_xor(p, 2);
    p += __shfl_xor(p, 4);
    p += __shfl_xor(p, 8);
    float dqv = (gc == 0) ? dq0
                : (gc == 1) ? dq1
                : (gc == 2) ? dq2
                : (gc == 3) ? dq3 : dq4;
    float v = (p + dqv) * (1.f / 24.f);
    v = (v >= 0.f) ? v : 0.2f * v;
    float ev = __expf(v);
    float4 vd = fp8x4_dec(V8[(size_t)c * 64 + lane]);
    acc.x += ev * vd.x;
    acc.y += ev * vd.y;
    acc.z += ev * vd.z;
    acc.w += ev * vd.w;
  }
  float invS = 1.f / sums[head];
  acc.x *= invS; acc.y *= invS; acc.z *= invS; acc.w *= invS;
  reinterpret_cast<float4*>(agg0)[lane] = acc;
}

// x1 = ((agg0 @ Wo2 + bo2 + x[0]) @ W1 + b1)
__global__ __launch_bounds__(256) void final_head_kernel(
    const float* __restrict__ agg0, const float* __restrict__ Wo2,
    const float* __restrict__ bo2, const float* __restrict__ x,
    const float* __restrict__ W1, const float* __restrict__ b1,
    float* __restrict__ x1) {
  __shared__ float a0[256];
  __shared__ float t1[256];
  int j = threadIdx.x;
  a0[j] = agg0[j];
  __syncthreads();
  float acc = bo2[j] + x[j];
  for (int k = 0; k < 256; k++) acc += a0[k] * Wo2[k * 256 + j];
  t1[j] = acc;
  __syncthreads();
  float acc2 = b1[j];
  for (int k = 0; k < 256; k++) acc2 += t1[k] * W1[k * 256 + j];
  x1[j] = acc2;
}

// ---------------- AO[b] = softmax_t(x1 . tok[b,t] / 16) @ tok[b] ------------
__global__ __launch_bounds__(256) void attn_out_kernel(
    const float* __restrict__ x1g, const float* __restrict__ tok,
    float* __restrict__ AO) {
  int b = blockIdx.x;
  int t = threadIdx.x;
  __shared__ float x1[256];
  __shared__ float w[256];
  __shared__ float red[256];
  x1[t] = x1g[t];
  __syncthreads();
  const float* tr = tok + (size_t)(b * 256 + t) * 256;
  float sc = 0.f;
  for (int d = 0; d < 256; d++) sc += x1[d] * tr[d];
  sc *= (1.f / 16.f);
  red[t] = sc;
  __syncthreads();
  for (int off = 128; off; off >>= 1) {
    if (t < off) red[t] = fmaxf(red[t], red[t + off]);
    __syncthreads();
  }
  float mx = red[0];
  __syncthreads();
  float ex = expf(sc - mx);
  red[t] = ex;
  __syncthreads();
  for (int off = 128; off; off >>= 1) {
    if (t < off) red[t] += red[t + off];
    __syncthreads();
  }
  w[t] = ex / red[0];
  __syncthreads();
  float acc = 0.f;
  for (int k = 0; k < 256; k++)
    acc += w[k] * tok[(size_t)(b * 256 + k) * 256 + t];
  AO[b * 256 + t] = acc;
}

// ---------------- y = AOflat @ Wout + bout; out_row = y @ W3 + b3; tile 25 --
__global__ __launch_bounds__(256) void final_out_kernel(
    const float* __restrict__ AO, const float* __restrict__ Wout,
    const float* __restrict__ bout, const float* __restrict__ W3,
    const float* __restrict__ b3, float* __restrict__ out) {
  __shared__ float a[1280];
  __shared__ float y[256];
  int j = threadIdx.x;
  for (int i = j; i < 1280; i += 256) a[i] = AO[i];
  __syncthreads();
  float acc = bout[j];
  for (int k = 0; k < 1280; k++) acc += a[k] * Wout[k * 256 + j];
  y[j] = acc;
  __syncthreads();
  for (int q = 0; q < 4; q++) {
    int t = j + q * 256;
    float o = b3[t];
    for (int k = 0; k < 256; k++) o += y[k] * W3[k * 1024 + t];
    for (int g = 0; g < 25; g++) out[(size_t)g * 1024 + t] = o;
  }
}

extern "C" void kernel_launch(void* const* d_in, const int* in_sizes, int n_in,
                              void* d_out, int out_size, void* d_ws,
                              size_t ws_size, hipStream_t stream) {
  const int* concept_ids = (const int*)d_in[0];
  const int* edge_index = (const int*)d_in[1];
  const float* sent = (const float*)d_in[3];
  const float* tokemb = (const float*)d_in[4];
  const int* batch = (const int*)d_in[5];
  const float* ent = (const float*)d_in[6];
  const float* Wq = (const float*)d_in[7];
  const float* bq = (const float*)d_in[8];
  const float* Wk = (const float*)d_in[9];
  const float* bk = (const float*)d_in[10];
  const float* Wv = (const float*)d_in[11];
  const float* bv = (const float*)d_in[12];
  const float* Ws = (const float*)d_in[13];
  const float* bs = (const float*)d_in[14];
  const float* Wo = (const float*)d_in[15];
  const float* bo = (const float*)d_in[16];
  const float* W1 = (const float*)d_in[17];
  const float* b1 = (const float*)d_in[18];
  const float* W2 = (const float*)d_in[19];
  const float* b2 = (const float*)d_in[20];
  const float* W3 = (const float*)d_in[21];
  const float* b3 = (const float*)d_in[22];
  const float* Wout = (const float*)d_in[23];
  const float* bout = (const float*)d_in[24];
  float* out = (float*)d_out;

  float* ws = (float*)d_ws;
  size_t off_ = 0;
  auto alloc = [&](size_t n) {
    float* p = ws + off_;
    off_ += n;
    return p;
  };
  float* x = alloc((size_t)NNODES * DM);
  float* x2 = alloc((size_t)NNODES * DM);
  float* Qf = alloc((size_t)NNODES * DM);
  unsigned short* xb = (unsigned short*)alloc((size_t)NNODES * DM / 2);
  unsigned short* aggb = (unsigned short*)alloc((size_t)NNODES * DM / 2);
  unsigned char* K8 = (unsigned char*)alloc((size_t)NNODES * DM / 4);
  unsigned char* V8 = (unsigned char*)alloc((size_t)NNODES * DM / 4);
  unsigned short* WT = (unsigned short*)alloc(12 * 65536 / 2);
  unsigned short* W2T = (unsigned short*)alloc(262144 / 2);
  unsigned short* tokb = (unsigned short*)alloc(1280 * 1024 / 2);
  float* tok = alloc(1280 * 256);
  float* QS5all = alloc(3 * 5 * 256);
  float* sums = alloc(16);
  float* agg0 = alloc(256);
  float* x1 = alloc(256);
  float* AO = alloc(1280);
  int* deg = (int*)alloc(NNODES);
  int* colPad = (int*)alloc((size_t)NNODES * PAD);

  // prep (all layer-invariant)
  gather_kernel<<<5000, 256, 0, stream>>>(concept_ids, ent, x, xb, NNODES);
  wtrans12_kernel<<<3072, 256, 0, stream>>>(Wq, Wk, Wv, Wo, WT);
  w2t_kernel<<<1024, 256, 0, stream>>>(W2, W2T);
  tokconv_kernel<<<1280, 256, 0, stream>>>(tokemb, tokb);
  hipMemsetAsync(deg, 0, NNODES * sizeof(int), stream);
  fill_kernel<<<(NEDGES + 255) / 256, 256, 0, stream>>>(edge_index, batch, deg,
                                                        colPad, NEDGES);
  {
    dim3 g(5, 3);
    qs5all_kernel<<<g, 256, 0, stream>>>(sent, Ws, bs, QS5all);
  }
  hipMemsetAsync(sums, 0, 12 * sizeof(float), stream);

  float* xin = x;
  float* xout = x2;
  for (int l = 0; l < 3; l++) {
    unsigned short* WoT = WT + (size_t)(l * 4 + 3) * 65536;
    {
      dim3 g(12, (NNODES + 63) / 64);
      qkv_gemm_kernel<<<g, 256, 0, stream>>>(
          xb, WT + (size_t)(l * 4) * 65536, bq + l * DM, bk + l * DM,
          bv + l * DM, Qf, K8, V8, NNODES);
    }
    if (l < 2) {
      fused_edge_kernel<1><<<5000, 256, 0, stream>>>(
          deg, colPad, batch, Qf, (const unsigned int*)K8,
          (const unsigned int*)V8, QS5all + l * 1280, sums + l * 4, aggb,
          NNODES);
      rescale_wo_kernel<<<256, 256, 0, stream>>>(WoT, sums + l * 4);
      dim3 g(4, (NNODES + 63) / 64);
      gemm_bf16_kernel<<<g, 256, 0, stream>>>(aggb, WoT, bo + l * DM, xin,
                                              xout, xb, NNODES, 256);
      float* tmp = xin;
      xin = xout;
      xout = tmp;
    } else {
      fused_edge_kernel<0><<<5000, 256, 0, stream>>>(
          deg, colPad, batch, Qf, (const unsigned int*)K8,
          (const unsigned int*)V8, QS5all + l * 1280, sums + l * 4, nullptr,
          NNODES);
      node0_agg_kernel<<<1, 64, 0, stream>>>(
          deg, colPad, batch, Qf, (const unsigned int*)K8,
          (const unsigned int*)V8, QS5all + l * 1280, sums + l * 4, agg0);
      final_head_kernel<<<1, 256, 0, stream>>>(agg0, Wo + (size_t)2 * 65536,
                                               bo + 2 * DM, xin, W1, b1, x1);
    }
  }

  // tok = token_embedding @ W2 + b2 via MFMA (M=1280, K=1024)
  {
    dim3 g(4, 1280 / 64);
    gemm_bf16_kernel<<<g, 256, 0, stream>>>(tokb, W2T, b2, nullptr, tok,
                                            nullptr, 1280, 1024);
  }
  attn_out_kernel<<<5, 256, 0, stream>>>(x1, tok, AO);
  final_out_kernel<<<1, 256, 0, stream>>>(AO, Wout, bout, W3, b3, out);
}

// Round 5
// 702.803 us; speedup vs baseline: 8.2462x; 1.2044x over previous
//
#include <hip/hip_runtime.h>
#include <hip/hip_bf16.h>

#define NNODES 20000
#define NEDGES 640000
#define DM 256
#define PAD 128

typedef short s16x8 __attribute__((ext_vector_type(8)));
typedef float f32x4 __attribute__((ext_vector_type(4)));
typedef float f32x2 __attribute__((ext_vector_type(2)));

__device__ inline float b2f(unsigned short u) {
  union { unsigned int i; float f; } z;
  z.i = (unsigned int)u << 16;
  return z.f;
}
__device__ inline unsigned short f2b(float f) {
  union { unsigned int i; float f; } z;
  z.f = f;
  unsigned int i = z.i;
  return (unsigned short)((i + 0x7FFFu + ((i >> 16) & 1u)) >> 16);
}

// ---------------- fp8 e4m3 encode/decode ------------------------------------
__device__ inline unsigned char f2fp8(float v) {
#if __has_builtin(__builtin_amdgcn_cvt_pk_fp8_f32)
  int t = __builtin_amdgcn_cvt_pk_fp8_f32(v, v, 0, false);
  return (unsigned char)(t & 0xFF);
#else
  union { float f; unsigned int u; } z;
  z.f = v;
  unsigned int s = (z.u >> 31) << 7;
  float av = fabsf(v);
  if (av >= 448.f) return (unsigned char)(s | 0x7E);
  if (av < 0.015625f) {
    int q = (int)rintf(av * 512.f);
    return (unsigned char)(s | (unsigned)q);
  }
  int e32 = (int)((z.u >> 23) & 255) - 127;
  unsigned mant = z.u & 0x7FFFFF;
  unsigned t = mant + 0x7FFFF + ((mant >> 20) & 1);
  if (t >= 0x800000u) { t = 0; e32++; }
  int e4 = e32 + 7;
  unsigned m3 = (t >> 20) & 7;
  if (e4 > 15 || (e4 == 15 && m3 == 7)) return (unsigned char)(s | 0x7E);
  return (unsigned char)(s | (unsigned)((e4 << 3) | m3));
#endif
}

__device__ inline float4 fp8x4_dec(unsigned int u) {
#if __has_builtin(__builtin_amdgcn_cvt_pk_f32_fp8)
  f32x2 lo = __builtin_amdgcn_cvt_pk_f32_fp8((int)u, false);
  f32x2 hi = __builtin_amdgcn_cvt_pk_f32_fp8((int)u, true);
  float4 r;
  r.x = lo[0]; r.y = lo[1]; r.z = hi[0]; r.w = hi[1];
  return r;
#else
  float4 r;
  float* p = &r.x;
#pragma unroll
  for (int j = 0; j < 4; j++) {
    unsigned b = (u >> (8 * j)) & 0xFF;
    unsigned s = b >> 7, e = (b >> 3) & 15, m = b & 7;
    float mag;
    if (e == 0) mag = (float)m * 0.001953125f;
    else {
      union { unsigned int i; float f; } z;
      z.i = ((e + 120u) << 23) | (m << 20);
      mag = z.f;
    }
    p[j] = s ? -mag : mag;
  }
  return r;
#endif
}

// ---------------- gather: x = ent[cid] (f32 + bf16) -------------------------
__global__ __launch_bounds__(256) void gather_kernel(
    const int* __restrict__ cid, const float* __restrict__ ent,
    float* __restrict__ x, unsigned short* __restrict__ xb, int n) {
  int idx = blockIdx.x * 256 + threadIdx.x;
  if (idx >= n * 64) return;
  int node = idx >> 6, d4 = idx & 63;
  float4 v = reinterpret_cast<const float4*>(ent)[(size_t)cid[node] * 64 + d4];
  reinterpret_cast<float4*>(x)[(size_t)node * 64 + d4] = v;
  ushort4 b;
  b.x = f2b(v.x); b.y = f2b(v.y); b.z = f2b(v.z); b.w = f2b(v.w);
  reinterpret_cast<ushort4*>(xb)[(size_t)node * 64 + d4] = b;
}

// ---------------- all 12 square weights -> bf16 [N][K] ----------------------
__global__ __launch_bounds__(256) void wtrans12_kernel(
    const float* __restrict__ Wq, const float* __restrict__ Wk,
    const float* __restrict__ Wv, const float* __restrict__ Wo,
    unsigned short* __restrict__ WT) {
  int slot = blockIdx.x >> 8;           // 0..11 = l*4 + t
  int l = slot >> 2, t = slot & 3;
  int n = blockIdx.x & 255;
  int k = threadIdx.x;
  const float* src = (t == 0) ? Wq : (t == 1) ? Wk : (t == 2) ? Wv : Wo;
  WT[(size_t)slot * 65536 + n * 256 + k] =
      f2b(src[(size_t)l * 65536 + k * 256 + n]);
}

// ---------------- W2 (1024x256) -> bf16 [256][1024] --------------------------
__global__ __launch_bounds__(256) void w2t_kernel(const float* __restrict__ W2,
                                                  unsigned short* __restrict__ W2T) {
  int i = blockIdx.x * 256 + threadIdx.x;  // 262144
  int n = i >> 10, k = i & 1023;
  W2T[n * 1024 + k] = f2b(W2[k * 256 + n]);
}

// ---------------- token_embedding f32 -> bf16 --------------------------------
__global__ __launch_bounds__(256) void tokconv_kernel(
    const float* __restrict__ te, unsigned short* __restrict__ tb) {
  int i = blockIdx.x * 256 + threadIdx.x;  // 327680 float4s
  float4 v = reinterpret_cast<const float4*>(te)[i];
  ushort4 b;
  b.x = f2b(v.x); b.y = f2b(v.y); b.z = f2b(v.z); b.w = f2b(v.w);
  reinterpret_cast<ushort4*>(tb)[i] = b;
}

// ---------------- padded-CSR fill: slot = atomicAdd(deg) --------------------
__global__ __launch_bounds__(256) void fill_kernel(const int* __restrict__ ei,
                                                   const int* __restrict__ batch,
                                                   int* __restrict__ deg,
                                                   int* __restrict__ colPad,
                                                   int E) {
  int e = blockIdx.x * 256 + threadIdx.x;
  if (e >= E) return;
  int r = ei[e];
  int c = ei[E + e];
  int slot = atomicAdd(&deg[r], 1);
  if (slot < PAD) colPad[(size_t)r * PAD + slot] = c | ((batch[c] / 5) << 24);
}

// ---------------- QS for all layers: QS5all[l][g][256] ----------------------
__global__ __launch_bounds__(256) void qs5all_kernel(
    const float* __restrict__ sent, const float* __restrict__ Ws,
    const float* __restrict__ bs, float* __restrict__ QS5all) {
  int g = blockIdx.x, l = blockIdx.y;
  int j = threadIdx.x;
  __shared__ float sh[1024];
  for (int i = j; i < 1024; i += 256) sh[i] = sent[g * 1024 + i];
  __syncthreads();
  const float* W = Ws + (size_t)l * 1024 * 256;
  float acc = bs[l * 256 + j];
  for (int k = 0; k < 1024; k++) acc += sh[k] * W[k * 256 + j];
  QS5all[(size_t)(l * 5 + g) * 256 + j] = acc;
}

// ---------------- fused QKV MFMA GEMM: [M,256] @ [256,768] ------------------
__global__ __launch_bounds__(256) void qkv_gemm_kernel(
    const unsigned short* __restrict__ A, const unsigned short* __restrict__ Bt,
    const float* __restrict__ bq, const float* __restrict__ bk,
    const float* __restrict__ bv, float* __restrict__ Qf,
    unsigned char* __restrict__ K8, unsigned char* __restrict__ V8, int M) {
  int wid = threadIdx.x >> 6;
  int lane = threadIdx.x & 63;
  int wr = wid >> 1, wc = wid & 1;
  int rowBase = blockIdx.y * 64 + wr * 32;
  int colBase = blockIdx.x * 64 + wc * 32;  // 0..767
  int r16 = lane & 15, kg = lane >> 4;
  f32x4 acc[2][2] = {};
  for (int k0 = 0; k0 < 256; k0 += 32) {
    s16x8 a[2], b[2];
#pragma unroll
    for (int mi = 0; mi < 2; mi++) {
      int r = rowBase + mi * 16 + r16;
      s16x8 z = {};
      a[mi] = (r < M) ? *reinterpret_cast<const s16x8*>(
                            &A[(size_t)r * 256 + k0 + kg * 8])
                      : z;
    }
#pragma unroll
    for (int ni = 0; ni < 2; ni++) {
      int c = colBase + ni * 16 + r16;
      b[ni] = *reinterpret_cast<const s16x8*>(&Bt[(size_t)c * 256 + k0 + kg * 8]);
    }
#pragma unroll
    for (int mi = 0; mi < 2; mi++)
#pragma unroll
      for (int ni = 0; ni < 2; ni++)
        acc[mi][ni] = __builtin_amdgcn_mfma_f32_16x16x32_bf16(
            a[mi], b[ni], acc[mi][ni], 0, 0, 0);
  }
  int region = (blockIdx.x * 64) >> 8;  // 0,1,2 (block never straddles)
  const float* bias = (region == 0) ? bq : (region == 1) ? bk : bv;
  unsigned char* dst8 = (region == 1) ? K8 : V8;
#pragma unroll
  for (int mi = 0; mi < 2; mi++)
#pragma unroll
    for (int ni = 0; ni < 2; ni++) {
      int cg = colBase + ni * 16 + (lane & 15);
      int cr = cg & 255;
      float bia = bias[cr];
#pragma unroll
      for (int reg = 0; reg < 4; reg++) {
        int r = rowBase + mi * 16 + (lane >> 4) * 4 + reg;
        if (r >= M) continue;
        float v = acc[mi][ni][reg] + bia;
        if (region == 0)
          Qf[(size_t)r * 256 + cr] = v;
        else
          dst8[(size_t)r * 256 + cr] = f2fp8(v);
      }
    }
}

// ---------------- generic MFMA GEMM: C = A@Bt^T + bias (+resid) -------------
__global__ __launch_bounds__(256) void gemm_bf16_kernel(
    const unsigned short* __restrict__ A, const unsigned short* __restrict__ Bt,
    const float* __restrict__ bias, const float* __restrict__ resid,
    float* __restrict__ Cf, unsigned short* __restrict__ Cb, int M, int K) {
  int wid = threadIdx.x >> 6;
  int lane = threadIdx.x & 63;
  int wr = wid >> 1, wc = wid & 1;
  int rowBase = blockIdx.y * 64 + wr * 32;
  int colBase = blockIdx.x * 64 + wc * 32;
  int r16 = lane & 15, kg = lane >> 4;
  f32x4 acc[2][2] = {};
  for (int k0 = 0; k0 < K; k0 += 32) {
    s16x8 a[2], b[2];
#pragma unroll
    for (int mi = 0; mi < 2; mi++) {
      int r = rowBase + mi * 16 + r16;
      s16x8 z = {};
      a[mi] = (r < M) ? *reinterpret_cast<const s16x8*>(
                            &A[(size_t)r * K + k0 + kg * 8])
                      : z;
    }
#pragma unroll
    for (int ni = 0; ni < 2; ni++) {
      int c = colBase + ni * 16 + r16;
      b[ni] = *reinterpret_cast<const s16x8*>(&Bt[(size_t)c * K + k0 + kg * 8]);
    }
#pragma unroll
    for (int mi = 0; mi < 2; mi++)
#pragma unroll
      for (int ni = 0; ni < 2; ni++)
        acc[mi][ni] = __builtin_amdgcn_mfma_f32_16x16x32_bf16(
            a[mi], b[ni], acc[mi][ni], 0, 0, 0);
  }
#pragma unroll
  for (int mi = 0; mi < 2; mi++)
#pragma unroll
    for (int ni = 0; ni < 2; ni++) {
      int c = colBase + ni * 16 + (lane & 15);
      float bia = bias[c];
#pragma unroll
      for (int reg = 0; reg < 4; reg++) {
        int r = rowBase + mi * 16 + (lane >> 4) * 4 + reg;
        if (r >= M) continue;
        float v = acc[mi][ni][reg] + bia;
        if (resid) v += resid[(size_t)r * 256 + c];
        if (Cf) Cf[(size_t)r * 256 + c] = v;
        if (Cb) Cb[(size_t)r * 256 + c] = f2b(v);
      }
    }
}

// ---------------- rescale WoT rows by 1/sums[head] (fold softmax norm) ------
__global__ __launch_bounds__(256) void rescale_wo_kernel(
    unsigned short* __restrict__ WoT, const float* __restrict__ sums) {
  int i = blockIdx.x * 256 + threadIdx.x;  // 65536
  int head = (i & 255) >> 6;
  WoT[i] = f2b(b2f(WoT[i]) / sums[head]);
}

// ---------------- fused edge pass (padded CSR, wave per node) ----------------
// 4-way edge unroll for ILP; node id forced wave-uniform (SGPR) so colPad/deg
// become scalar loads. fp8 K/V.
template <int DO_AGG>
__global__ __launch_bounds__(256) void fused_edge_kernel(
    const int* __restrict__ deg, const int* __restrict__ colPad,
    const int* __restrict__ batch, const float* __restrict__ Q,
    const unsigned int* __restrict__ K8, const unsigned int* __restrict__ V8,
    const float* __restrict__ QS5, float* __restrict__ sums,
    unsigned short* __restrict__ aggb, int n) {
  int wv = __builtin_amdgcn_readfirstlane(threadIdx.x >> 6);  // wave in block
  int node = blockIdx.x * 4 + wv;  // SGPR-uniform
  int lane = threadIdx.x & 63;
  int head = lane >> 4;
  float sum0 = 0.f, sum1 = 0.f, sum2 = 0.f, sum3 = 0.f;
  float4 a0 = {0.f, 0.f, 0.f, 0.f}, a1 = a0, a2 = a0, a3 = a0;
  float4 qe = a0;
  float dq0 = 0.f, dq1 = 0.f, dq2 = 0.f, dq3 = 0.f, dq4 = 0.f;
  int dcount = 0;
  if (node < n) {
    float4 q = reinterpret_cast<const float4*>(Q)[(size_t)node * 64 + lane];
    int gr = batch[node] / 5;
    float4 qs = reinterpret_cast<const float4*>(QS5)[gr * 64 + lane];
    qe.x = q.x + qs.x; qe.y = q.y + qs.y; qe.z = q.z + qs.z; qe.w = q.w + qs.w;
#pragma unroll
    for (int g = 0; g < 5; g++) {
      float4 w = reinterpret_cast<const float4*>(QS5)[g * 64 + lane];
      float d = q.x * w.x + q.y * w.y + q.z * w.z + q.w * w.w;
      d += __shfl_xor(d, 1);
      d += __shfl_xor(d, 2);
      d += __shfl_xor(d, 4);
      d += __shfl_xor(d, 8);
      if (g == 0) dq0 = d;
      else if (g == 1) dq1 = d;
      else if (g == 2) dq2 = d;
      else if (g == 3) dq3 = d;
      else dq4 = d;
    }
    dcount = deg[node];
    if (dcount > PAD) dcount = PAD;
  }
  const int* myCol = colPad + (size_t)node * PAD;
  bool lead = (lane & 15) == 0;
  int m = 0;
  for (; m + 4 <= dcount; m += 4) {
    int cc0 = myCol[m + 0], cc1 = myCol[m + 1];
    int cc2 = myCol[m + 2], cc3 = myCol[m + 3];
    int c0 = cc0 & 0xFFFFFF, c1 = cc1 & 0xFFFFFF;
    int c2 = cc2 & 0xFFFFFF, c3 = cc3 & 0xFFFFFF;
    // issue all raw loads up front
    unsigned int kr0 = K8[(size_t)c0 * 64 + lane];
    unsigned int kr1 = K8[(size_t)c1 * 64 + lane];
    unsigned int kr2 = K8[(size_t)c2 * 64 + lane];
    unsigned int kr3 = K8[(size_t)c3 * 64 + lane];
    unsigned int vr0 = 0, vr1 = 0, vr2 = 0, vr3 = 0;
    if (DO_AGG) {
      vr0 = V8[(size_t)c0 * 64 + lane];
      vr1 = V8[(size_t)c1 * 64 + lane];
      vr2 = V8[(size_t)c2 * 64 + lane];
      vr3 = V8[(size_t)c3 * 64 + lane];
    }
    float4 kd0 = fp8x4_dec(kr0), kd1 = fp8x4_dec(kr1);
    float4 kd2 = fp8x4_dec(kr2), kd3 = fp8x4_dec(kr3);
    float p0 = qe.x * kd0.x + qe.y * kd0.y + qe.z * kd0.z + qe.w * kd0.w;
    float p1 = qe.x * kd1.x + qe.y * kd1.y + qe.z * kd1.z + qe.w * kd1.w;
    float p2 = qe.x * kd2.x + qe.y * kd2.y + qe.z * kd2.z + qe.w * kd2.w;
    float p3 = qe.x * kd3.x + qe.y * kd3.y + qe.z * kd3.z + qe.w * kd3.w;
    p0 += __shfl_xor(p0, 1); p1 += __shfl_xor(p1, 1);
    p2 += __shfl_xor(p2, 1); p3 += __shfl_xor(p3, 1);
    p0 += __shfl_xor(p0, 2); p1 += __shfl_xor(p1, 2);
    p2 += __shfl_xor(p2, 2); p3 += __shfl_xor(p3, 2);
    p0 += __shfl_xor(p0, 4); p1 += __shfl_xor(p1, 4);
    p2 += __shfl_xor(p2, 4); p3 += __shfl_xor(p3, 4);
    p0 += __shfl_xor(p0, 8); p1 += __shfl_xor(p1, 8);
    p2 += __shfl_xor(p2, 8); p3 += __shfl_xor(p3, 8);
    int gc0 = cc0 >> 24, gc1 = cc1 >> 24, gc2 = cc2 >> 24, gc3 = cc3 >> 24;
    float dv0 = (gc0 == 0) ? dq0 : (gc0 == 1) ? dq1 : (gc0 == 2) ? dq2 : (gc0 == 3) ? dq3 : dq4;
    float dv1 = (gc1 == 0) ? dq0 : (gc1 == 1) ? dq1 : (gc1 == 2) ? dq2 : (gc1 == 3) ? dq3 : dq4;
    float dv2 = (gc2 == 0) ? dq0 : (gc2 == 1) ? dq1 : (gc2 == 2) ? dq2 : (gc2 == 3) ? dq3 : dq4;
    float dv3 = (gc3 == 0) ? dq0 : (gc3 == 1) ? dq1 : (gc3 == 2) ? dq2 : (gc3 == 3) ? dq3 : dq4;
    float v0 = (p0 + dv0) * (1.f / 24.f); v0 = (v0 >= 0.f) ? v0 : 0.2f * v0;
    float v1 = (p1 + dv1) * (1.f / 24.f); v1 = (v1 >= 0.f) ? v1 : 0.2f * v1;
    float v2 = (p2 + dv2) * (1.f / 24.f); v2 = (v2 >= 0.f) ? v2 : 0.2f * v2;
    float v3 = (p3 + dv3) * (1.f / 24.f); v3 = (v3 >= 0.f) ? v3 : 0.2f * v3;
    float e0 = __expf(v0), e1 = __expf(v1), e2 = __expf(v2), e3 = __expf(v3);
    if (lead) { sum0 += e0; sum1 += e1; sum2 += e2; sum3 += e3; }
    if (DO_AGG) {
      float4 vd0 = fp8x4_dec(vr0), vd1 = fp8x4_dec(vr1);
      float4 vd2 = fp8x4_dec(vr2), vd3 = fp8x4_dec(vr3);
      a0.x += e0 * vd0.x; a0.y += e0 * vd0.y; a0.z += e0 * vd0.z; a0.w += e0 * vd0.w;
      a1.x += e1 * vd1.x; a1.y += e1 * vd1.y; a1.z += e1 * vd1.z; a1.w += e1 * vd1.w;
      a2.x += e2 * vd2.x; a2.y += e2 * vd2.y; a2.z += e2 * vd2.z; a2.w += e2 * vd2.w;
      a3.x += e3 * vd3.x; a3.y += e3 * vd3.y; a3.z += e3 * vd3.z; a3.w += e3 * vd3.w;
    }
  }
  for (; m < dcount; m++) {
    int cc = myCol[m];
    int c = cc & 0xFFFFFF, gc = cc >> 24;
    float4 kd = fp8x4_dec(K8[(size_t)c * 64 + lane]);
    float p = qe.x * kd.x + qe.y * kd.y + qe.z * kd.z + qe.w * kd.w;
    p += __shfl_xor(p, 1);
    p += __shfl_xor(p, 2);
    p += __shfl_xor(p, 4);
    p += __shfl_xor(p, 8);
    float dqv = (gc == 0) ? dq0 : (gc == 1) ? dq1 : (gc == 2) ? dq2
                : (gc == 3) ? dq3 : dq4;
    float v = (p + dqv) * (1.f / 24.f);
    v = (v >= 0.f) ? v : 0.2f * v;
    float ev = __expf(v);
    if (lead) sum0 += ev;
    if (DO_AGG) {
      float4 vd = fp8x4_dec(V8[(size_t)c * 64 + lane]);
      a0.x += ev * vd.x; a0.y += ev * vd.y; a0.z += ev * vd.z; a0.w += ev * vd.w;
    }
  }
  float sumExp = (sum0 + sum1) + (sum2 + sum3);
  if (DO_AGG && node < n) {
    float4 acc;
    acc.x = (a0.x + a1.x) + (a2.x + a3.x);
    acc.y = (a0.y + a1.y) + (a2.y + a3.y);
    acc.z = (a0.z + a1.z) + (a2.z + a3.z);
    acc.w = (a0.w + a1.w) + (a2.w + a3.w);
    ushort4 b;
    b.x = f2b(acc.x); b.y = f2b(acc.y); b.z = f2b(acc.z); b.w = f2b(acc.w);
    reinterpret_cast<ushort4*>(aggb)[(size_t)node * 64 + lane] = b;
  }
  __shared__ float red[4][4];
  int w = threadIdx.x >> 6;
  if (lead) red[w][head] = sumExp;
  __syncthreads();
  if (threadIdx.x < 4) {
    float t = red[0][threadIdx.x] + red[1][threadIdx.x] + red[2][threadIdx.x] +
              red[3][threadIdx.x];
    atomicAdd(&sums[threadIdx.x], t);
  }
}

// ---------------- layer-2: agg for node 0 only ------------------------------
__global__ __launch_bounds__(64) void node0_agg_kernel(
    const int* __restrict__ deg, const int* __restrict__ colPad,
    const int* __restrict__ batch, const float* __restrict__ Q,
    const unsigned int* __restrict__ K8, const unsigned int* __restrict__ V8,
    const float* __restrict__ QS5, const float* __restrict__ sums,
    float* __restrict__ agg0) {
  int lane = threadIdx.x;
  int head = lane >> 4;
  float4 q = reinterpret_cast<const float4*>(Q)[lane];
  int gr = batch[0] / 5;
  float4 qs = reinterpret_cast<const float4*>(QS5)[gr * 64 + lane];
  float4 qe = {q.x + qs.x, q.y + qs.y, q.z + qs.z, q.w + qs.w};
  float dq0 = 0.f, dq1 = 0.f, dq2 = 0.f, dq3 = 0.f, dq4 = 0.f;
#pragma unroll
  for (int g = 0; g < 5; g++) {
    float4 w = reinterpret_cast<const float4*>(QS5)[g * 64 + lane];
    float d = q.x * w.x + q.y * w.y + q.z * w.z + q.w * w.w;
    d += __shfl_xor(d, 1);
    d += __shfl_xor(d, 2);
    d += __shfl_xor(d, 4);
    d += __shfl_xor(d, 8);
    if (g == 0) dq0 = d;
    else if (g == 1) dq1 = d;
    else if (g == 2) dq2 = d;
    else if (g == 3) dq3 = d;
    else dq4 = d;
  }
  float4 acc = {0.f, 0.f, 0.f, 0.f};
  int dcount = deg[0];
  if (dcount > PAD) dcount = PAD;
  for (int m = 0; m < dcount; m++) {
    int cc = colPad[m];
    int c = cc & 0xFFFFFF, gc = cc >> 24;
    float4 kd = fp8x4_dec(K8[(size_t)c * 64 + lane]);
    float p = qe.x * kd.x + qe.y * kd.y + qe.z * kd.z + qe.w * kd.w;
    p += __shfl_xor(p, 1);
    p += __shfl_xor(p, 2);
    p += __shfl_xor(p, 4);
    p += __shfl_xor(p, 8);
    float dqv = (gc == 0) ? dq0
                : (gc == 1) ? dq1
                : (gc == 2) ? dq2
                : (gc == 3) ? dq3 : dq4;
    float v = (p + dqv) * (1.f / 24.f);
    v = (v >= 0.f) ? v : 0.2f * v;
    float ev = __expf(v);
    float4 vd = fp8x4_dec(V8[(size_t)c * 64 + lane]);
    acc.x += ev * vd.x;
    acc.y += ev * vd.y;
    acc.z += ev * vd.z;
    acc.w += ev * vd.w;
  }
  float invS = 1.f / sums[head];
  acc.x *= invS; acc.y *= invS; acc.z *= invS; acc.w *= invS;
  reinterpret_cast<float4*>(agg0)[lane] = acc;
}

// x1 = ((agg0 @ Wo2 + bo2 + x[0]) @ W1 + b1)
__global__ __launch_bounds__(256) void final_head_kernel(
    const float* __restrict__ agg0, const float* __restrict__ Wo2,
    const float* __restrict__ bo2, const float* __restrict__ x,
    const float* __restrict__ W1, const float* __restrict__ b1,
    float* __restrict__ x1) {
  __shared__ float a0[256];
  __shared__ float t1[256];
  int j = threadIdx.x;
  a0[j] = agg0[j];
  __syncthreads();
  float acc = bo2[j] + x[j];
  for (int k = 0; k < 256; k++) acc += a0[k] * Wo2[k * 256 + j];
  t1[j] = acc;
  __syncthreads();
  float acc2 = b1[j];
  for (int k = 0; k < 256; k++) acc2 += t1[k] * W1[k * 256 + j];
  x1[j] = acc2;
}

// ---------------- AO[b] = softmax_t(x1 . tok[b,t] / 16) @ tok[b] ------------
__global__ __launch_bounds__(256) void attn_out_kernel(
    const float* __restrict__ x1g, const float* __restrict__ tok,
    float* __restrict__ AO) {
  int b = blockIdx.x;
  int t = threadIdx.x;
  __shared__ float x1[256];
  __shared__ float w[256];
  __shared__ float red[256];
  x1[t] = x1g[t];
  __syncthreads();
  const float* tr = tok + (size_t)(b * 256 + t) * 256;
  float sc = 0.f;
  for (int d = 0; d < 256; d++) sc += x1[d] * tr[d];
  sc *= (1.f / 16.f);
  red[t] = sc;
  __syncthreads();
  for (int off = 128; off; off >>= 1) {
    if (t < off) red[t] = fmaxf(red[t], red[t + off]);
    __syncthreads();
  }
  float mx = red[0];
  __syncthreads();
  float ex = expf(sc - mx);
  red[t] = ex;
  __syncthreads();
  for (int off = 128; off; off >>= 1) {
    if (t < off) red[t] += red[t + off];
    __syncthreads();
  }
  w[t] = ex / red[0];
  __syncthreads();
  float acc = 0.f;
  for (int k = 0; k < 256; k++)
    acc += w[k] * tok[(size_t)(b * 256 + k) * 256 + t];
  AO[b * 256 + t] = acc;
}

// ---------------- y = AOflat @ Wout + bout; out_row = y @ W3 + b3; tile 25 --
__global__ __launch_bounds__(256) void final_out_kernel(
    const float* __restrict__ AO, const float* __restrict__ Wout,
    const float* __restrict__ bout, const float* __restrict__ W3,
    const float* __restrict__ b3, float* __restrict__ out) {
  __shared__ float a[1280];
  __shared__ float y[256];
  int j = threadIdx.x;
  for (int i = j; i < 1280; i += 256) a[i] = AO[i];
  __syncthreads();
  float acc = bout[j];
  for (int k = 0; k < 1280; k++) acc += a[k] * Wout[k * 256 + j];
  y[j] = acc;
  __syncthreads();
  for (int q = 0; q < 4; q++) {
    int t = j + q * 256;
    float o = b3[t];
    for (int k = 0; k < 256; k++) o += y[k] * W3[k * 1024 + t];
    for (int g = 0; g < 25; g++) out[(size_t)g * 1024 + t] = o;
  }
}

extern "C" void kernel_launch(void* const* d_in, const int* in_sizes, int n_in,
                              void* d_out, int out_size, void* d_ws,
                              size_t ws_size, hipStream_t stream) {
  const int* concept_ids = (const int*)d_in[0];
  const int* edge_index = (const int*)d_in[1];
  const float* sent = (const float*)d_in[3];
  const float* tokemb = (const float*)d_in[4];
  const int* batch = (const int*)d_in[5];
  const float* ent = (const float*)d_in[6];
  const float* Wq = (const float*)d_in[7];
  const float* bq = (const float*)d_in[8];
  const float* Wk = (const float*)d_in[9];
  const float* bk = (const float*)d_in[10];
  const float* Wv = (const float*)d_in[11];
  const float* bv = (const float*)d_in[12];
  const float* Ws = (const float*)d_in[13];
  const float* bs = (const float*)d_in[14];
  const float* Wo = (const float*)d_in[15];
  const float* bo = (const float*)d_in[16];
  const float* W1 = (const float*)d_in[17];
  const float* b1 = (const float*)d_in[18];
  const float* W2 = (const float*)d_in[19];
  const float* b2 = (const float*)d_in[20];
  const float* W3 = (const float*)d_in[21];
  const float* b3 = (const float*)d_in[22];
  const float* Wout = (const float*)d_in[23];
  const float* bout = (const float*)d_in[24];
  float* out = (float*)d_out;

  float* ws = (float*)d_ws;
  size_t off_ = 0;
  auto alloc = [&](size_t n) {
    float* p = ws + off_;
    off_ += n;
    return p;
  };
  float* x = alloc((size_t)NNODES * DM);
  float* x2 = alloc((size_t)NNODES * DM);
  float* Qf = alloc((size_t)NNODES * DM);
  unsigned short* xb = (unsigned short*)alloc((size_t)NNODES * DM / 2);
  unsigned short* aggb = (unsigned short*)alloc((size_t)NNODES * DM / 2);
  unsigned char* K8 = (unsigned char*)alloc((size_t)NNODES * DM / 4);
  unsigned char* V8 = (unsigned char*)alloc((size_t)NNODES * DM / 4);
  unsigned short* WT = (unsigned short*)alloc(12 * 65536 / 2);
  unsigned short* W2T = (unsigned short*)alloc(262144 / 2);
  unsigned short* tokb = (unsigned short*)alloc(1280 * 1024 / 2);
  float* tok = alloc(1280 * 256);
  float* QS5all = alloc(3 * 5 * 256);
  float* sums = alloc(16);
  float* agg0 = alloc(256);
  float* x1 = alloc(256);
  float* AO = alloc(1280);
  int* deg = (int*)alloc(NNODES);
  int* colPad = (int*)alloc((size_t)NNODES * PAD);

  // prep (all layer-invariant)
  gather_kernel<<<5000, 256, 0, stream>>>(concept_ids, ent, x, xb, NNODES);
  wtrans12_kernel<<<3072, 256, 0, stream>>>(Wq, Wk, Wv, Wo, WT);
  w2t_kernel<<<1024, 256, 0, stream>>>(W2, W2T);
  tokconv_kernel<<<1280, 256, 0, stream>>>(tokemb, tokb);
  hipMemsetAsync(deg, 0, NNODES * sizeof(int), stream);
  fill_kernel<<<(NEDGES + 255) / 256, 256, 0, stream>>>(edge_index, batch, deg,
                                                        colPad, NEDGES);
  {
    dim3 g(5, 3);
    qs5all_kernel<<<g, 256, 0, stream>>>(sent, Ws, bs, QS5all);
  }
  hipMemsetAsync(sums, 0, 12 * sizeof(float), stream);

  float* xin = x;
  float* xout = x2;
  for (int l = 0; l < 3; l++) {
    unsigned short* WoT = WT + (size_t)(l * 4 + 3) * 65536;
    {
      dim3 g(12, (NNODES + 63) / 64);
      qkv_gemm_kernel<<<g, 256, 0, stream>>>(
          xb, WT + (size_t)(l * 4) * 65536, bq + l * DM, bk + l * DM,
          bv + l * DM, Qf, K8, V8, NNODES);
    }
    if (l < 2) {
      fused_edge_kernel<1><<<5000, 256, 0, stream>>>(
          deg, colPad, batch, Qf, (const unsigned int*)K8,
          (const unsigned int*)V8, QS5all + l * 1280, sums + l * 4, aggb,
          NNODES);
      rescale_wo_kernel<<<256, 256, 0, stream>>>(WoT, sums + l * 4);
      dim3 g(4, (NNODES + 63) / 64);
      gemm_bf16_kernel<<<g, 256, 0, stream>>>(aggb, WoT, bo + l * DM, xin,
                                              xout, xb, NNODES, 256);
      float* tmp = xin;
      xin = xout;
      xout = tmp;
    } else {
      fused_edge_kernel<0><<<5000, 256, 0, stream>>>(
          deg, colPad, batch, Qf, (const unsigned int*)K8,
          (const unsigned int*)V8, QS5all + l * 1280, sums + l * 4, nullptr,
          NNODES);
      node0_agg_kernel<<<1, 64, 0, stream>>>(
          deg, colPad, batch, Qf, (const unsigned int*)K8,
          (const unsigned int*)V8, QS5all + l * 1280, sums + l * 4, agg0);
      final_head_kernel<<<1, 256, 0, stream>>>(agg0, Wo + (size_t)2 * 65536,
                                               bo + 2 * DM, xin, W1, b1, x1);
    }
  }

  // tok = token_embedding @ W2 + b2 via MFMA (M=1280, K=1024)
  {
    dim3 g(4, 1280 / 64);
    gemm_bf16_kernel<<<g, 256, 0, stream>>>(tokb, W2T, b2, nullptr, tok,
                                            nullptr, 1280, 1024);
  }
  attn_out_kernel<<<5, 256, 0, stream>>>(x1, tok, AO);
  final_out_kernel<<<1, 256, 0, stream>>>(AO, Wout, bout, W3, b3, out);
}

// Round 6
// 657.796 us; speedup vs baseline: 8.8104x; 1.0684x over previous
//
#include <hip/hip_runtime.h>
#include <hip/hip_bf16.h>

#define NNODES 20000
#define NEDGES 640000
#define DM 256
#define PAD 128

typedef short s16x8 __attribute__((ext_vector_type(8)));
typedef float f32x4 __attribute__((ext_vector_type(4)));
typedef float f32x2 __attribute__((ext_vector_type(2)));

__device__ inline float b2f(unsigned short u) {
  union { unsigned int i; float f; } z;
  z.i = (unsigned int)u << 16;
  return z.f;
}
__device__ inline unsigned short f2b(float f) {
  union { unsigned int i; float f; } z;
  z.f = f;
  unsigned int i = z.i;
  return (unsigned short)((i + 0x7FFFu + ((i >> 16) & 1u)) >> 16);
}

// ---------------- fp8 e4m3 encode/decode ------------------------------------
__device__ inline unsigned char f2fp8(float v) {
#if __has_builtin(__builtin_amdgcn_cvt_pk_fp8_f32)
  int t = __builtin_amdgcn_cvt_pk_fp8_f32(v, v, 0, false);
  return (unsigned char)(t & 0xFF);
#else
  union { float f; unsigned int u; } z;
  z.f = v;
  unsigned int s = (z.u >> 31) << 7;
  float av = fabsf(v);
  if (av >= 448.f) return (unsigned char)(s | 0x7E);
  if (av < 0.015625f) {
    int q = (int)rintf(av * 512.f);
    return (unsigned char)(s | (unsigned)q);
  }
  int e32 = (int)((z.u >> 23) & 255) - 127;
  unsigned mant = z.u & 0x7FFFFF;
  unsigned t = mant + 0x7FFFF + ((mant >> 20) & 1);
  if (t >= 0x800000u) { t = 0; e32++; }
  int e4 = e32 + 7;
  unsigned m3 = (t >> 20) & 7;
  if (e4 > 15 || (e4 == 15 && m3 == 7)) return (unsigned char)(s | 0x7E);
  return (unsigned char)(s | (unsigned)((e4 << 3) | m3));
#endif
}

__device__ inline float4 fp8x4_dec(unsigned int u) {
#if __has_builtin(__builtin_amdgcn_cvt_pk_f32_fp8)
  f32x2 lo = __builtin_amdgcn_cvt_pk_f32_fp8((int)u, false);
  f32x2 hi = __builtin_amdgcn_cvt_pk_f32_fp8((int)u, true);
  float4 r;
  r.x = lo[0]; r.y = lo[1]; r.z = hi[0]; r.w = hi[1];
  return r;
#else
  float4 r;
  float* p = &r.x;
#pragma unroll
  for (int j = 0; j < 4; j++) {
    unsigned b = (u >> (8 * j)) & 0xFF;
    unsigned s = b >> 7, e = (b >> 3) & 15, m = b & 7;
    float mag;
    if (e == 0) mag = (float)m * 0.001953125f;
    else {
      union { unsigned int i; float f; } z;
      z.i = ((e + 120u) << 23) | (m << 20);
      mag = z.f;
    }
    p[j] = s ? -mag : mag;
  }
  return r;
#endif
}

// ---------------- gather: x = ent[cid] (f32 + bf16) -------------------------
__global__ __launch_bounds__(256) void gather_kernel(
    const int* __restrict__ cid, const float* __restrict__ ent,
    float* __restrict__ x, unsigned short* __restrict__ xb, int n) {
  int idx = blockIdx.x * 256 + threadIdx.x;
  if (idx >= n * 64) return;
  int node = idx >> 6, d4 = idx & 63;
  float4 v = reinterpret_cast<const float4*>(ent)[(size_t)cid[node] * 64 + d4];
  reinterpret_cast<float4*>(x)[(size_t)node * 64 + d4] = v;
  ushort4 b;
  b.x = f2b(v.x); b.y = f2b(v.y); b.z = f2b(v.z); b.w = f2b(v.w);
  reinterpret_cast<ushort4*>(xb)[(size_t)node * 64 + d4] = b;
}

// ---------------- all 12 square weights -> bf16 [N][K] ----------------------
__global__ __launch_bounds__(256) void wtrans12_kernel(
    const float* __restrict__ Wq, const float* __restrict__ Wk,
    const float* __restrict__ Wv, const float* __restrict__ Wo,
    unsigned short* __restrict__ WT) {
  int slot = blockIdx.x >> 8;           // 0..11 = l*4 + t
  int l = slot >> 2, t = slot & 3;
  int n = blockIdx.x & 255;
  int k = threadIdx.x;
  const float* src = (t == 0) ? Wq : (t == 1) ? Wk : (t == 2) ? Wv : Wo;
  WT[(size_t)slot * 65536 + n * 256 + k] =
      f2b(src[(size_t)l * 65536 + k * 256 + n]);
}

// ---------------- W2 (1024x256) -> bf16 [256][1024] --------------------------
__global__ __launch_bounds__(256) void w2t_kernel(const float* __restrict__ W2,
                                                  unsigned short* __restrict__ W2T) {
  int i = blockIdx.x * 256 + threadIdx.x;  // 262144
  int n = i >> 10, k = i & 1023;
  W2T[n * 1024 + k] = f2b(W2[k * 256 + n]);
}

// ---------------- token_embedding f32 -> bf16 --------------------------------
__global__ __launch_bounds__(256) void tokconv_kernel(
    const float* __restrict__ te, unsigned short* __restrict__ tb) {
  int i = blockIdx.x * 256 + threadIdx.x;  // 327680 float4s
  float4 v = reinterpret_cast<const float4*>(te)[i];
  ushort4 b;
  b.x = f2b(v.x); b.y = f2b(v.y); b.z = f2b(v.z); b.w = f2b(v.w);
  reinterpret_cast<ushort4*>(tb)[i] = b;
}

// ---------------- padded-CSR fill: slot = atomicAdd(deg) --------------------
__global__ __launch_bounds__(256) void fill_kernel(const int* __restrict__ ei,
                                                   const int* __restrict__ batch,
                                                   int* __restrict__ deg,
                                                   int* __restrict__ colPad,
                                                   int E) {
  int e = blockIdx.x * 256 + threadIdx.x;
  if (e >= E) return;
  int r = ei[e];
  int c = ei[E + e];
  int slot = atomicAdd(&deg[r], 1);
  if (slot < PAD) colPad[(size_t)r * PAD + slot] = c | ((batch[c] / 5) << 24);
}

// ---------------- QS for all layers: QS5all[l][g][256] ----------------------
__global__ __launch_bounds__(256) void qs5all_kernel(
    const float* __restrict__ sent, const float* __restrict__ Ws,
    const float* __restrict__ bs, float* __restrict__ QS5all) {
  int g = blockIdx.x, l = blockIdx.y;
  int j = threadIdx.x;
  __shared__ float sh[1024];
  for (int i = j; i < 1024; i += 256) sh[i] = sent[g * 1024 + i];
  __syncthreads();
  const float* W = Ws + (size_t)l * 1024 * 256;
  float acc = bs[l * 256 + j];
  for (int k = 0; k < 1024; k++) acc += sh[k] * W[k * 256 + j];
  QS5all[(size_t)(l * 5 + g) * 256 + j] = acc;
}

// ---------------- fused QKV MFMA GEMM: [M,256] @ [256,768] ------------------
__global__ __launch_bounds__(256) void qkv_gemm_kernel(
    const unsigned short* __restrict__ A, const unsigned short* __restrict__ Bt,
    const float* __restrict__ bq, const float* __restrict__ bk,
    const float* __restrict__ bv, float* __restrict__ Qf,
    unsigned char* __restrict__ K8, unsigned char* __restrict__ V8, int M) {
  int wid = threadIdx.x >> 6;
  int lane = threadIdx.x & 63;
  int wr = wid >> 1, wc = wid & 1;
  int rowBase = blockIdx.y * 64 + wr * 32;
  int colBase = blockIdx.x * 64 + wc * 32;  // 0..767
  int r16 = lane & 15, kg = lane >> 4;
  f32x4 acc[2][2] = {};
  for (int k0 = 0; k0 < 256; k0 += 32) {
    s16x8 a[2], b[2];
#pragma unroll
    for (int mi = 0; mi < 2; mi++) {
      int r = rowBase + mi * 16 + r16;
      s16x8 z = {};
      a[mi] = (r < M) ? *reinterpret_cast<const s16x8*>(
                            &A[(size_t)r * 256 + k0 + kg * 8])
                      : z;
    }
#pragma unroll
    for (int ni = 0; ni < 2; ni++) {
      int c = colBase + ni * 16 + r16;
      b[ni] = *reinterpret_cast<const s16x8*>(&Bt[(size_t)c * 256 + k0 + kg * 8]);
    }
#pragma unroll
    for (int mi = 0; mi < 2; mi++)
#pragma unroll
      for (int ni = 0; ni < 2; ni++)
        acc[mi][ni] = __builtin_amdgcn_mfma_f32_16x16x32_bf16(
            a[mi], b[ni], acc[mi][ni], 0, 0, 0);
  }
  int region = (blockIdx.x * 64) >> 8;  // 0,1,2 (block never straddles)
  const float* bias = (region == 0) ? bq : (region == 1) ? bk : bv;
  unsigned char* dst8 = (region == 1) ? K8 : V8;
#pragma unroll
  for (int mi = 0; mi < 2; mi++)
#pragma unroll
    for (int ni = 0; ni < 2; ni++) {
      int cg = colBase + ni * 16 + (lane & 15);
      int cr = cg & 255;
      float bia = bias[cr];
#pragma unroll
      for (int reg = 0; reg < 4; reg++) {
        int r = rowBase + mi * 16 + (lane >> 4) * 4 + reg;
        if (r >= M) continue;
        float v = acc[mi][ni][reg] + bia;
        if (region == 0)
          Qf[(size_t)r * 256 + cr] = v;
        else
          dst8[(size_t)r * 256 + cr] = f2fp8(v);
      }
    }
}

// ---------------- generic MFMA GEMM: C = A@Bt^T + bias (+resid) -------------
__global__ __launch_bounds__(256) void gemm_bf16_kernel(
    const unsigned short* __restrict__ A, const unsigned short* __restrict__ Bt,
    const float* __restrict__ bias, const float* __restrict__ resid,
    float* __restrict__ Cf, unsigned short* __restrict__ Cb, int M, int K) {
  int wid = threadIdx.x >> 6;
  int lane = threadIdx.x & 63;
  int wr = wid >> 1, wc = wid & 1;
  int rowBase = blockIdx.y * 64 + wr * 32;
  int colBase = blockIdx.x * 64 + wc * 32;
  int r16 = lane & 15, kg = lane >> 4;
  f32x4 acc[2][2] = {};
  for (int k0 = 0; k0 < K; k0 += 32) {
    s16x8 a[2], b[2];
#pragma unroll
    for (int mi = 0; mi < 2; mi++) {
      int r = rowBase + mi * 16 + r16;
      s16x8 z = {};
      a[mi] = (r < M) ? *reinterpret_cast<const s16x8*>(
                            &A[(size_t)r * K + k0 + kg * 8])
                      : z;
    }
#pragma unroll
    for (int ni = 0; ni < 2; ni++) {
      int c = colBase + ni * 16 + r16;
      b[ni] = *reinterpret_cast<const s16x8*>(&Bt[(size_t)c * K + k0 + kg * 8]);
    }
#pragma unroll
    for (int mi = 0; mi < 2; mi++)
#pragma unroll
      for (int ni = 0; ni < 2; ni++)
        acc[mi][ni] = __builtin_amdgcn_mfma_f32_16x16x32_bf16(
            a[mi], b[ni], acc[mi][ni], 0, 0, 0);
  }
#pragma unroll
  for (int mi = 0; mi < 2; mi++)
#pragma unroll
    for (int ni = 0; ni < 2; ni++) {
      int c = colBase + ni * 16 + (lane & 15);
      float bia = bias[c];
#pragma unroll
      for (int reg = 0; reg < 4; reg++) {
        int r = rowBase + mi * 16 + (lane >> 4) * 4 + reg;
        if (r >= M) continue;
        float v = acc[mi][ni][reg] + bia;
        if (resid) v += resid[(size_t)r * 256 + c];
        if (Cf) Cf[(size_t)r * 256 + c] = v;
        if (Cb) Cb[(size_t)r * 256 + c] = f2b(v);
      }
    }
}

// ---------------- rescale WoT rows by 1/sums[head] (fold softmax norm) ------
__global__ __launch_bounds__(256) void rescale_wo_kernel(
    unsigned short* __restrict__ WoT, const float* __restrict__ sums) {
  int i = blockIdx.x * 256 + threadIdx.x;  // 65536
  int head = (i & 255) >> 6;
  WoT[i] = f2b(b2f(WoT[i]) / sums[head]);
}

// ---------------- fused edge pass (padded CSR, wave per node) ----------------
template <int DO_AGG>
__global__ __launch_bounds__(256) void fused_edge_kernel(
    const int* __restrict__ deg, const int* __restrict__ colPad,
    const int* __restrict__ batch, const float* __restrict__ Q,
    const unsigned int* __restrict__ K8, const unsigned int* __restrict__ V8,
    const float* __restrict__ QS5, float* __restrict__ sums,
    unsigned short* __restrict__ aggb, int n) {
  int wv = __builtin_amdgcn_readfirstlane(threadIdx.x >> 6);  // wave in block
  int node = blockIdx.x * 4 + wv;  // SGPR-uniform
  int lane = threadIdx.x & 63;
  int head = lane >> 4;
  float sum0 = 0.f, sum1 = 0.f, sum2 = 0.f, sum3 = 0.f;
  float4 a0 = {0.f, 0.f, 0.f, 0.f}, a1 = a0, a2 = a0, a3 = a0;
  float4 qe = a0;
  float dq0 = 0.f, dq1 = 0.f, dq2 = 0.f, dq3 = 0.f, dq4 = 0.f;
  int dcount = 0;
  if (node < n) {
    float4 q = reinterpret_cast<const float4*>(Q)[(size_t)node * 64 + lane];
    int gr = batch[node] / 5;
    float4 qs = reinterpret_cast<const float4*>(QS5)[gr * 64 + lane];
    qe.x = q.x + qs.x; qe.y = q.y + qs.y; qe.z = q.z + qs.z; qe.w = q.w + qs.w;
#pragma unroll
    for (int g = 0; g < 5; g++) {
      float4 w = reinterpret_cast<const float4*>(QS5)[g * 64 + lane];
      float d = q.x * w.x + q.y * w.y + q.z * w.z + q.w * w.w;
      d += __shfl_xor(d, 1);
      d += __shfl_xor(d, 2);
      d += __shfl_xor(d, 4);
      d += __shfl_xor(d, 8);
      if (g == 0) dq0 = d;
      else if (g == 1) dq1 = d;
      else if (g == 2) dq2 = d;
      else if (g == 3) dq3 = d;
      else dq4 = d;
    }
    dcount = deg[node];
    if (dcount > PAD) dcount = PAD;
  }
  const int* myCol = colPad + (size_t)node * PAD;
  bool lead = (lane & 15) == 0;
  int m = 0;
  for (; m + 4 <= dcount; m += 4) {
    int cc0 = myCol[m + 0], cc1 = myCol[m + 1];
    int cc2 = myCol[m + 2], cc3 = myCol[m + 3];
    int c0 = cc0 & 0xFFFFFF, c1 = cc1 & 0xFFFFFF;
    int c2 = cc2 & 0xFFFFFF, c3 = cc3 & 0xFFFFFF;
    unsigned int kr0 = K8[(size_t)c0 * 64 + lane];
    unsigned int kr1 = K8[(size_t)c1 * 64 + lane];
    unsigned int kr2 = K8[(size_t)c2 * 64 + lane];
    unsigned int kr3 = K8[(size_t)c3 * 64 + lane];
    unsigned int vr0 = 0, vr1 = 0, vr2 = 0, vr3 = 0;
    if (DO_AGG) {
      vr0 = V8[(size_t)c0 * 64 + lane];
      vr1 = V8[(size_t)c1 * 64 + lane];
      vr2 = V8[(size_t)c2 * 64 + lane];
      vr3 = V8[(size_t)c3 * 64 + lane];
    }
    float4 kd0 = fp8x4_dec(kr0), kd1 = fp8x4_dec(kr1);
    float4 kd2 = fp8x4_dec(kr2), kd3 = fp8x4_dec(kr3);
    float p0 = qe.x * kd0.x + qe.y * kd0.y + qe.z * kd0.z + qe.w * kd0.w;
    float p1 = qe.x * kd1.x + qe.y * kd1.y + qe.z * kd1.z + qe.w * kd1.w;
    float p2 = qe.x * kd2.x + qe.y * kd2.y + qe.z * kd2.z + qe.w * kd2.w;
    float p3 = qe.x * kd3.x + qe.y * kd3.y + qe.z * kd3.z + qe.w * kd3.w;
    p0 += __shfl_xor(p0, 1); p1 += __shfl_xor(p1, 1);
    p2 += __shfl_xor(p2, 1); p3 += __shfl_xor(p3, 1);
    p0 += __shfl_xor(p0, 2); p1 += __shfl_xor(p1, 2);
    p2 += __shfl_xor(p2, 2); p3 += __shfl_xor(p3, 2);
    p0 += __shfl_xor(p0, 4); p1 += __shfl_xor(p1, 4);
    p2 += __shfl_xor(p2, 4); p3 += __shfl_xor(p3, 4);
    p0 += __shfl_xor(p0, 8); p1 += __shfl_xor(p1, 8);
    p2 += __shfl_xor(p2, 8); p3 += __shfl_xor(p3, 8);
    int gc0 = cc0 >> 24, gc1 = cc1 >> 24, gc2 = cc2 >> 24, gc3 = cc3 >> 24;
    float dv0 = (gc0 == 0) ? dq0 : (gc0 == 1) ? dq1 : (gc0 == 2) ? dq2 : (gc0 == 3) ? dq3 : dq4;
    float dv1 = (gc1 == 0) ? dq0 : (gc1 == 1) ? dq1 : (gc1 == 2) ? dq2 : (gc1 == 3) ? dq3 : dq4;
    float dv2 = (gc2 == 0) ? dq0 : (gc2 == 1) ? dq1 : (gc2 == 2) ? dq2 : (gc2 == 3) ? dq3 : dq4;
    float dv3 = (gc3 == 0) ? dq0 : (gc3 == 1) ? dq1 : (gc3 == 2) ? dq2 : (gc3 == 3) ? dq3 : dq4;
    float v0 = (p0 + dv0) * (1.f / 24.f); v0 = (v0 >= 0.f) ? v0 : 0.2f * v0;
    float v1 = (p1 + dv1) * (1.f / 24.f); v1 = (v1 >= 0.f) ? v1 : 0.2f * v1;
    float v2 = (p2 + dv2) * (1.f / 24.f); v2 = (v2 >= 0.f) ? v2 : 0.2f * v2;
    float v3 = (p3 + dv3) * (1.f / 24.f); v3 = (v3 >= 0.f) ? v3 : 0.2f * v3;
    float e0 = __expf(v0), e1 = __expf(v1), e2 = __expf(v2), e3 = __expf(v3);
    if (lead) { sum0 += e0; sum1 += e1; sum2 += e2; sum3 += e3; }
    if (DO_AGG) {
      float4 vd0 = fp8x4_dec(vr0), vd1 = fp8x4_dec(vr1);
      float4 vd2 = fp8x4_dec(vr2), vd3 = fp8x4_dec(vr3);
      a0.x += e0 * vd0.x; a0.y += e0 * vd0.y; a0.z += e0 * vd0.z; a0.w += e0 * vd0.w;
      a1.x += e1 * vd1.x; a1.y += e1 * vd1.y; a1.z += e1 * vd1.z; a1.w += e1 * vd1.w;
      a2.x += e2 * vd2.x; a2.y += e2 * vd2.y; a2.z += e2 * vd2.z; a2.w += e2 * vd2.w;
      a3.x += e3 * vd3.x; a3.y += e3 * vd3.y; a3.z += e3 * vd3.z; a3.w += e3 * vd3.w;
    }
  }
  for (; m < dcount; m++) {
    int cc = myCol[m];
    int c = cc & 0xFFFFFF, gc = cc >> 24;
    float4 kd = fp8x4_dec(K8[(size_t)c * 64 + lane]);
    float p = qe.x * kd.x + qe.y * kd.y + qe.z * kd.z + qe.w * kd.w;
    p += __shfl_xor(p, 1);
    p += __shfl_xor(p, 2);
    p += __shfl_xor(p, 4);
    p += __shfl_xor(p, 8);
    float dqv = (gc == 0) ? dq0 : (gc == 1) ? dq1 : (gc == 2) ? dq2
                : (gc == 3) ? dq3 : dq4;
    float v = (p + dqv) * (1.f / 24.f);
    v = (v >= 0.f) ? v : 0.2f * v;
    float ev = __expf(v);
    if (lead) sum0 += ev;
    if (DO_AGG) {
      float4 vd = fp8x4_dec(V8[(size_t)c * 64 + lane]);
      a0.x += ev * vd.x; a0.y += ev * vd.y; a0.z += ev * vd.z; a0.w += ev * vd.w;
    }
  }
  float sumExp = (sum0 + sum1) + (sum2 + sum3);
  if (DO_AGG && node < n) {
    float4 acc;
    acc.x = (a0.x + a1.x) + (a2.x + a3.x);
    acc.y = (a0.y + a1.y) + (a2.y + a3.y);
    acc.z = (a0.z + a1.z) + (a2.z + a3.z);
    acc.w = (a0.w + a1.w) + (a2.w + a3.w);
    ushort4 b;
    b.x = f2b(acc.x); b.y = f2b(acc.y); b.z = f2b(acc.z); b.w = f2b(acc.w);
    reinterpret_cast<ushort4*>(aggb)[(size_t)node * 64 + lane] = b;
  }
  __shared__ float red[4][4];
  int w = threadIdx.x >> 6;
  if (lead) red[w][head] = sumExp;
  __syncthreads();
  if (threadIdx.x < 4) {
    float t = red[0][threadIdx.x] + red[1][threadIdx.x] + red[2][threadIdx.x] +
              red[3][threadIdx.x];
    atomicAdd(&sums[threadIdx.x], t);
  }
}

// ---------------- layer-2: agg for node 0 only ------------------------------
__global__ __launch_bounds__(64) void node0_agg_kernel(
    const int* __restrict__ deg, const int* __restrict__ colPad,
    const int* __restrict__ batch, const float* __restrict__ Q,
    const unsigned int* __restrict__ K8, const unsigned int* __restrict__ V8,
    const float* __restrict__ QS5, const float* __restrict__ sums,
    float* __restrict__ agg0) {
  int lane = threadIdx.x;
  int head = lane >> 4;
  float4 q = reinterpret_cast<const float4*>(Q)[lane];
  int gr = batch[0] / 5;
  float4 qs = reinterpret_cast<const float4*>(QS5)[gr * 64 + lane];
  float4 qe = {q.x + qs.x, q.y + qs.y, q.z + qs.z, q.w + qs.w};
  float dq0 = 0.f, dq1 = 0.f, dq2 = 0.f, dq3 = 0.f, dq4 = 0.f;
#pragma unroll
  for (int g = 0; g < 5; g++) {
    float4 w = reinterpret_cast<const float4*>(QS5)[g * 64 + lane];
    float d = q.x * w.x + q.y * w.y + q.z * w.z + q.w * w.w;
    d += __shfl_xor(d, 1);
    d += __shfl_xor(d, 2);
    d += __shfl_xor(d, 4);
    d += __shfl_xor(d, 8);
    if (g == 0) dq0 = d;
    else if (g == 1) dq1 = d;
    else if (g == 2) dq2 = d;
    else if (g == 3) dq3 = d;
    else dq4 = d;
  }
  float4 acc = {0.f, 0.f, 0.f, 0.f};
  int dcount = deg[0];
  if (dcount > PAD) dcount = PAD;
  for (int m = 0; m < dcount; m++) {
    int cc = colPad[m];
    int c = cc & 0xFFFFFF, gc = cc >> 24;
    float4 kd = fp8x4_dec(K8[(size_t)c * 64 + lane]);
    float p = qe.x * kd.x + qe.y * kd.y + qe.z * kd.z + qe.w * kd.w;
    p += __shfl_xor(p, 1);
    p += __shfl_xor(p, 2);
    p += __shfl_xor(p, 4);
    p += __shfl_xor(p, 8);
    float dqv = (gc == 0) ? dq0
                : (gc == 1) ? dq1
                : (gc == 2) ? dq2
                : (gc == 3) ? dq3 : dq4;
    float v = (p + dqv) * (1.f / 24.f);
    v = (v >= 0.f) ? v : 0.2f * v;
    float ev = __expf(v);
    float4 vd = fp8x4_dec(V8[(size_t)c * 64 + lane]);
    acc.x += ev * vd.x;
    acc.y += ev * vd.y;
    acc.z += ev * vd.z;
    acc.w += ev * vd.w;
  }
  float invS = 1.f / sums[head];
  acc.x *= invS; acc.y *= invS; acc.z *= invS; acc.w *= invS;
  reinterpret_cast<float4*>(agg0)[lane] = acc;
}

// x1 = ((agg0 @ Wo2 + bo2 + x[0]) @ W1 + b1), 1024 threads, 4-way k-split
__global__ __launch_bounds__(1024) void final_head_kernel(
    const float* __restrict__ agg0, const float* __restrict__ Wo2,
    const float* __restrict__ bo2, const float* __restrict__ x,
    const float* __restrict__ W1, const float* __restrict__ b1,
    float* __restrict__ x1) {
  __shared__ float a0[256];
  __shared__ float t1[256];
  __shared__ float part[4][256];
  int tid = threadIdx.x;
  int j = tid & 255, s = tid >> 8;
  if (tid < 256) a0[tid] = agg0[tid];
  __syncthreads();
  float acc = 0.f;
#pragma unroll 8
  for (int k = s * 64; k < s * 64 + 64; k++) acc += a0[k] * Wo2[k * 256 + j];
  part[s][j] = acc;
  __syncthreads();
  if (tid < 256)
    t1[tid] = part[0][tid] + part[1][tid] + part[2][tid] + part[3][tid] +
              bo2[tid] + x[tid];
  __syncthreads();
  float acc2 = 0.f;
#pragma unroll 8
  for (int k = s * 64; k < s * 64 + 64; k++) acc2 += t1[k] * W1[k * 256 + j];
  part[s][j] = acc2;
  __syncthreads();
  if (tid < 256)
    x1[tid] = part[0][tid] + part[1][tid] + part[2][tid] + part[3][tid] +
              b1[tid];
}

// ---------------- AO[b] = softmax_t(x1 . tok[b,t] / 16) @ tok[b] ------------
// scores: 16 lanes per row (coalesced float4); PV loop coalesced over t.
__global__ __launch_bounds__(256) void attn_out_kernel(
    const float* __restrict__ x1g, const float* __restrict__ tok,
    float* __restrict__ AO) {
  int b = blockIdx.x;
  int tid = threadIdx.x;
  int wave = tid >> 6, lane = tid & 63;
  int sub = lane >> 4, l16 = lane & 15;
  __shared__ float x1s[256];
  __shared__ float scs[256];
  __shared__ float red[256];
  __shared__ float wgt[256];
  x1s[tid] = x1g[tid];
  __syncthreads();
  const float4* xv4 = reinterpret_cast<const float4*>(x1s);
  for (int it = 0; it < 16; it++) {
    int row = wave * 64 + it * 4 + sub;
    const float4* tr =
        reinterpret_cast<const float4*>(tok + (size_t)(b * 256 + row) * 256);
    float sc = 0.f;
#pragma unroll
    for (int q = 0; q < 4; q++) {
      float4 v = tr[l16 + q * 16];
      float4 xv = xv4[l16 + q * 16];
      sc += v.x * xv.x + v.y * xv.y + v.z * xv.z + v.w * xv.w;
    }
    sc += __shfl_xor(sc, 1);
    sc += __shfl_xor(sc, 2);
    sc += __shfl_xor(sc, 4);
    sc += __shfl_xor(sc, 8);
    if (l16 == 0) scs[row] = sc * (1.f / 16.f);
  }
  __syncthreads();
  float sc = scs[tid];
  red[tid] = sc;
  __syncthreads();
  for (int off = 128; off; off >>= 1) {
    if (tid < off) red[tid] = fmaxf(red[tid], red[tid + off]);
    __syncthreads();
  }
  float mx = red[0];
  __syncthreads();
  float ex = expf(sc - mx);
  red[tid] = ex;
  __syncthreads();
  for (int off = 128; off; off >>= 1) {
    if (tid < off) red[tid] += red[tid + off];
    __syncthreads();
  }
  wgt[tid] = ex / red[0];
  __syncthreads();
  float acc = 0.f;
#pragma unroll 4
  for (int k = 0; k < 256; k++)
    acc += wgt[k] * tok[(size_t)(b * 256 + k) * 256 + tid];
  AO[b * 256 + tid] = acc;
}

// ---------------- final: partial[s][j] = sum_{k in slice s} AO[k]*Wout[k][j] -
__global__ __launch_bounds__(256) void final_y_kernel(
    const float* __restrict__ AO, const float* __restrict__ Wout,
    float* __restrict__ partial) {
  int s = blockIdx.x;  // 0..15, 80 rows each
  int j = threadIdx.x;
  __shared__ float a[80];
  if (threadIdx.x < 80) a[threadIdx.x] = AO[s * 80 + threadIdx.x];
  __syncthreads();
  const float* W = Wout + (size_t)s * 80 * 256;
  float acc = 0.f;
#pragma unroll 8
  for (int k = 0; k < 80; k++) acc += a[k] * W[k * 256 + j];
  partial[s * 256 + j] = acc;
}

// ---------------- out: y = reduce(partial)+bout; o = y@W3 + b3; 25 copies ---
__global__ __launch_bounds__(256) void final_out2_kernel(
    const float* __restrict__ partial, const float* __restrict__ bout,
    const float* __restrict__ W3, const float* __restrict__ b3,
    float* __restrict__ out) {
  __shared__ float y[256];
  int j = threadIdx.x;
  float acc = bout[j];
#pragma unroll
  for (int s = 0; s < 16; s++) acc += partial[s * 256 + j];
  y[j] = acc;
  __syncthreads();
  int t = blockIdx.x * 256 + j;
  float o = b3[t];
#pragma unroll 8
  for (int k = 0; k < 256; k++) o += y[k] * W3[k * 1024 + t];
  for (int g = 0; g < 25; g++) out[(size_t)g * 1024 + t] = o;
}

extern "C" void kernel_launch(void* const* d_in, const int* in_sizes, int n_in,
                              void* d_out, int out_size, void* d_ws,
                              size_t ws_size, hipStream_t stream) {
  const int* concept_ids = (const int*)d_in[0];
  const int* edge_index = (const int*)d_in[1];
  const float* sent = (const float*)d_in[3];
  const float* tokemb = (const float*)d_in[4];
  const int* batch = (const int*)d_in[5];
  const float* ent = (const float*)d_in[6];
  const float* Wq = (const float*)d_in[7];
  const float* bq = (const float*)d_in[8];
  const float* Wk = (const float*)d_in[9];
  const float* bk = (const float*)d_in[10];
  const float* Wv = (const float*)d_in[11];
  const float* bv = (const float*)d_in[12];
  const float* Ws = (const float*)d_in[13];
  const float* bs = (const float*)d_in[14];
  const float* Wo = (const float*)d_in[15];
  const float* bo = (const float*)d_in[16];
  const float* W1 = (const float*)d_in[17];
  const float* b1 = (const float*)d_in[18];
  const float* W2 = (const float*)d_in[19];
  const float* b2 = (const float*)d_in[20];
  const float* W3 = (const float*)d_in[21];
  const float* b3 = (const float*)d_in[22];
  const float* Wout = (const float*)d_in[23];
  const float* bout = (const float*)d_in[24];
  float* out = (float*)d_out;

  float* ws = (float*)d_ws;
  size_t off_ = 0;
  auto alloc = [&](size_t n) {
    float* p = ws + off_;
    off_ += n;
    return p;
  };
  float* x = alloc((size_t)NNODES * DM);
  float* x2 = alloc((size_t)NNODES * DM);
  float* Qf = alloc((size_t)NNODES * DM);
  unsigned short* xb = (unsigned short*)alloc((size_t)NNODES * DM / 2);
  unsigned short* aggb = (unsigned short*)alloc((size_t)NNODES * DM / 2);
  unsigned char* K8 = (unsigned char*)alloc((size_t)NNODES * DM / 4);
  unsigned char* V8 = (unsigned char*)alloc((size_t)NNODES * DM / 4);
  unsigned short* WT = (unsigned short*)alloc(12 * 65536 / 2);
  unsigned short* W2T = (unsigned short*)alloc(262144 / 2);
  unsigned short* tokb = (unsigned short*)alloc(1280 * 1024 / 2);
  float* tok = alloc(1280 * 256);
  float* QS5all = alloc(3 * 5 * 256);
  float* sums = alloc(16);
  float* agg0 = alloc(256);
  float* x1 = alloc(256);
  float* AO = alloc(1280);
  float* partial = alloc(16 * 256);
  int* deg = (int*)alloc(NNODES);
  int* colPad = (int*)alloc((size_t)NNODES * PAD);

  // prep (all layer-invariant)
  gather_kernel<<<5000, 256, 0, stream>>>(concept_ids, ent, x, xb, NNODES);
  wtrans12_kernel<<<3072, 256, 0, stream>>>(Wq, Wk, Wv, Wo, WT);
  w2t_kernel<<<1024, 256, 0, stream>>>(W2, W2T);
  tokconv_kernel<<<1280, 256, 0, stream>>>(tokemb, tokb);
  hipMemsetAsync(deg, 0, NNODES * sizeof(int), stream);
  fill_kernel<<<(NEDGES + 255) / 256, 256, 0, stream>>>(edge_index, batch, deg,
                                                        colPad, NEDGES);
  {
    dim3 g(5, 3);
    qs5all_kernel<<<g, 256, 0, stream>>>(sent, Ws, bs, QS5all);
  }
  hipMemsetAsync(sums, 0, 12 * sizeof(float), stream);

  float* xin = x;
  float* xout = x2;
  for (int l = 0; l < 3; l++) {
    unsigned short* WoT = WT + (size_t)(l * 4 + 3) * 65536;
    {
      dim3 g(12, (NNODES + 63) / 64);
      qkv_gemm_kernel<<<g, 256, 0, stream>>>(
          xb, WT + (size_t)(l * 4) * 65536, bq + l * DM, bk + l * DM,
          bv + l * DM, Qf, K8, V8, NNODES);
    }
    if (l < 2) {
      fused_edge_kernel<1><<<5000, 256, 0, stream>>>(
          deg, colPad, batch, Qf, (const unsigned int*)K8,
          (const unsigned int*)V8, QS5all + l * 1280, sums + l * 4, aggb,
          NNODES);
      rescale_wo_kernel<<<256, 256, 0, stream>>>(WoT, sums + l * 4);
      dim3 g(4, (NNODES + 63) / 64);
      gemm_bf16_kernel<<<g, 256, 0, stream>>>(aggb, WoT, bo + l * DM, xin,
                                              xout, xb, NNODES, 256);
      float* tmp = xin;
      xin = xout;
      xout = tmp;
    } else {
      fused_edge_kernel<0><<<5000, 256, 0, stream>>>(
          deg, colPad, batch, Qf, (const unsigned int*)K8,
          (const unsigned int*)V8, QS5all + l * 1280, sums + l * 4, nullptr,
          NNODES);
      node0_agg_kernel<<<1, 64, 0, stream>>>(
          deg, colPad, batch, Qf, (const unsigned int*)K8,
          (const unsigned int*)V8, QS5all + l * 1280, sums + l * 4, agg0);
      final_head_kernel<<<1, 1024, 0, stream>>>(agg0, Wo + (size_t)2 * 65536,
                                                bo + 2 * DM, xin, W1, b1, x1);
    }
  }

  // tok = token_embedding @ W2 + b2 via MFMA (M=1280, K=1024)
  {
    dim3 g(4, 1280 / 64);
    gemm_bf16_kernel<<<g, 256, 0, stream>>>(tokb, W2T, b2, nullptr, tok,
                                            nullptr, 1280, 1024);
  }
  attn_out_kernel<<<5, 256, 0, stream>>>(x1, tok, AO);
  final_y_kernel<<<16, 256, 0, stream>>>(AO, Wout, partial);
  final_out2_kernel<<<4, 256, 0, stream>>>(partial, bout, W3, b3, out);
}